// Round 1
// baseline (965.102 us; speedup 1.0000x reference)
//
#include <hip/hip_runtime.h>

typedef unsigned short u16;
typedef unsigned int u32;
typedef __bf16 bf16x8 __attribute__((ext_vector_type(8)));
typedef float f32x4 __attribute__((ext_vector_type(4)));

#define S_LEN 4096
#define HDIM 2048
#define KVDIM 512
#define N_HEADS 16
#define HEAD_D 128

__device__ __forceinline__ u16 f2bf(float f) {
  u32 u = __float_as_uint(f);
  u32 r = (u + 0x7FFFu + ((u >> 16) & 1u)) >> 16;
  return (u16)r;
}
__device__ __forceinline__ float bf2f(u16 h) {
  return __uint_as_float(((u32)h) << 16);
}

// ---------------- f32 -> bf16 cast (8 elems/thread) ----------------
__global__ void k_cast_bf16(const float* __restrict__ in, u16* __restrict__ out, int n8) {
  int i = blockIdx.x * blockDim.x + threadIdx.x;
  if (i >= n8) return;
  const float4* p = reinterpret_cast<const float4*>(in) + (size_t)i * 2;
  float4 a = p[0], b = p[1];
  u32 o0 = (u32)f2bf(a.x) | ((u32)f2bf(a.y) << 16);
  u32 o1 = (u32)f2bf(a.z) | ((u32)f2bf(a.w) << 16);
  u32 o2 = (u32)f2bf(b.x) | ((u32)f2bf(b.y) << 16);
  u32 o3 = (u32)f2bf(b.z) | ((u32)f2bf(b.w) << 16);
  reinterpret_cast<uint4*>(out)[i] = make_uint4(o0, o1, o2, o3);
}

// ---------------- W [Kd][Nd] f32 -> Wt [Nd][Kd] bf16 ----------------
__global__ void k_transpose_cast(const float* __restrict__ W, u16* __restrict__ Wt,
                                 int Kd, int Nd) {
  __shared__ float t[32][33];
  int bx = blockIdx.x, by = blockIdx.y;
  int tx = threadIdx.x, ty = threadIdx.y;
  int n = bx * 32 + tx;
  for (int j = ty; j < 32; j += 8)
    t[j][tx] = W[(size_t)(by * 32 + j) * Nd + n];
  __syncthreads();
  int k = by * 32 + tx;
  for (int j = ty; j < 32; j += 8)
    Wt[(size_t)(bx * 32 + j) * Kd + k] = f2bf(t[tx][j]);
}

// ---------------- RoPE table: cos/sin [S][64] f32 ----------------
__global__ void k_rope_table(float* __restrict__ cosT, float* __restrict__ sinT) {
  int i = blockIdx.x * blockDim.x + threadIdx.x;  // S*64
  int pos = i >> 6, f = i & 63;
  float inv = expf(-0.1439115683121279f * (float)f);  // 10000^(-f/64)
  float ang = (float)pos * inv;
  float s, c;
  sincosf(ang, &s, &c);
  cosT[i] = c;
  sinT[i] = s;
}

// ---------------- interleaved RoPE in-place on bf16 [S][width] ----------------
__global__ void k_rope_apply(u16* __restrict__ X, const float* __restrict__ cosT,
                             const float* __restrict__ sinT, int width) {
  int i = blockIdx.x * blockDim.x + threadIdx.x;  // S*width/8 threads
  size_t idx = (size_t)i * 8;
  int row = (int)(idx / width);
  int col = (int)(idx - (size_t)row * width);
  int fi = (col & 127) >> 1;  // multiple of 4
  float4 c4 = *reinterpret_cast<const float4*>(&cosT[(row << 6) + fi]);
  float4 s4 = *reinterpret_cast<const float4*>(&sinT[(row << 6) + fi]);
  uint4 v = *reinterpret_cast<const uint4*>(&X[idx]);
  float cc[4] = {c4.x, c4.y, c4.z, c4.w};
  float ss[4] = {s4.x, s4.y, s4.z, s4.w};
  u32 w_[4] = {v.x, v.y, v.z, v.w};
  u32 r_[4];
#pragma unroll
  for (int p = 0; p < 4; ++p) {
    float x1 = bf2f((u16)(w_[p] & 0xffff));
    float x2 = bf2f((u16)(w_[p] >> 16));
    float r1 = x1 * cc[p] - x2 * ss[p];
    float r2 = x1 * ss[p] + x2 * cc[p];
    r_[p] = (u32)f2bf(r1) | ((u32)f2bf(r2) << 16);
  }
  *reinterpret_cast<uint4*>(&X[idx]) = make_uint4(r_[0], r_[1], r_[2], r_[3]);
}

// ---------------- GEMM: C[M][N] = A[M][K](bf16) * Bt[N][K](bf16)^T ----------------
// 128x128 tile, BK=32, 4 waves (2x2), each wave 64x64 = 4x4 MFMA 16x16x32 tiles.
template <int BF16_OUT>
__global__ __launch_bounds__(256) void k_gemm_bt(
    const u16* __restrict__ A, const u16* __restrict__ Bt, void* __restrict__ Cout,
    int M, int N, int Kd) {
  constexpr int LDT = 40;  // padded k-stride (80B, 16B-aligned, bank-friendly)
  __shared__ __align__(16) u16 As[128 * LDT];
  __shared__ __align__(16) u16 Bs[128 * LDT];
  const int bm = blockIdx.x * 128;
  const int bn = blockIdx.y * 128;
  const int tid = threadIdx.x;
  const int lane = tid & 63;
  const int wid = tid >> 6;
  const int wr = (wid >> 1) * 64, wc = (wid & 1) * 64;
  const int lr = lane & 15, lhi = lane >> 4;
  f32x4 acc[4][4] = {};
  for (int k0 = 0; k0 < Kd; k0 += 32) {
#pragma unroll
    for (int it = 0; it < 2; ++it) {
      int t2 = it * 256 + tid;
      int row = t2 >> 2;
      int kc = (t2 & 3) * 8;
      *reinterpret_cast<uint4*>(&As[row * LDT + kc]) =
          *reinterpret_cast<const uint4*>(&A[(size_t)(bm + row) * Kd + k0 + kc]);
      *reinterpret_cast<uint4*>(&Bs[row * LDT + kc]) =
          *reinterpret_cast<const uint4*>(&Bt[(size_t)(bn + row) * Kd + k0 + kc]);
    }
    __syncthreads();
    bf16x8 af[4], bfr[4];
#pragma unroll
    for (int m = 0; m < 4; ++m)
      af[m] = *reinterpret_cast<const bf16x8*>(&As[(wr + m * 16 + lr) * LDT + lhi * 8]);
#pragma unroll
    for (int n = 0; n < 4; ++n)
      bfr[n] = *reinterpret_cast<const bf16x8*>(&Bs[(wc + n * 16 + lr) * LDT + lhi * 8]);
#pragma unroll
    for (int m = 0; m < 4; ++m)
#pragma unroll
      for (int n = 0; n < 4; ++n)
        acc[m][n] = __builtin_amdgcn_mfma_f32_16x16x32_bf16(af[m], bfr[n], acc[m][n], 0, 0, 0);
    __syncthreads();
  }
#pragma unroll
  for (int m = 0; m < 4; ++m) {
#pragma unroll
    for (int r = 0; r < 4; ++r) {
      int grow = bm + wr + m * 16 + lhi * 4 + r;
#pragma unroll
      for (int n = 0; n < 4; ++n) {
        int gcol = bn + wc + n * 16 + lr;
        float v = acc[m][n][r];
        if (BF16_OUT)
          reinterpret_cast<u16*>(Cout)[(size_t)grow * N + gcol] = f2bf(v);
        else
          reinterpret_cast<float*>(Cout)[(size_t)grow * N + gcol] = v;
      }
    }
  }
}

// ---------------- flash attention (causal, GQA) ----------------
// grid (S/64, 16 heads), 256 threads = 4 waves; wave owns 16 q-rows.
__global__ __launch_bounds__(256) void k_attn(
    const u16* __restrict__ Q, const u16* __restrict__ K, const u16* __restrict__ V,
    u16* __restrict__ O) {
  constexpr int KLD = 136;  // K-tile row stride (272B: 16B aligned, 2-way banks)
  constexpr int VLD = 40;   // Vt row stride
  constexpr int PLD = 40;   // P row stride
  __shared__ __align__(16) u16 Ks[32 * KLD];
  __shared__ __align__(16) u16 Vt[128 * VLD];
  __shared__ __align__(16) u16 Pl[4][16 * PLD];
  const int h = blockIdx.y;
  const int kvh = h >> 2;
  const int q0 = blockIdx.x * 64;
  const int tid = threadIdx.x, lane = tid & 63, wid = tid >> 6;
  const int lr = lane & 15, lhi = lane >> 4;
  const int qbase = q0 + wid * 16;
  bf16x8 qf[4];
#pragma unroll
  for (int c = 0; c < 4; ++c)
    qf[c] = *reinterpret_cast<const bf16x8*>(
        &Q[(size_t)(qbase + lr) * HDIM + h * HEAD_D + c * 32 + lhi * 8]);
  f32x4 o_[8] = {};
  float m_[4] = {-3e38f, -3e38f, -3e38f, -3e38f};
  float l_[4] = {0.f, 0.f, 0.f, 0.f};
  const int nsteps = (q0 + 64) >> 5;
  const float scale = 0.08838834764831845f;  // 1/sqrt(128)
  for (int t = 0; t < nsteps; ++t) {
    const int kb = t << 5;
    // stage K (padded rows) and V transposed
#pragma unroll
    for (int it = 0; it < 2; ++it) {
      int t2 = it * 256 + tid;
      int row = t2 >> 4;        // kv row 0..31
      int col = (t2 & 15) * 8;  // d 0..120
      *reinterpret_cast<uint4*>(&Ks[row * KLD + col]) =
          *reinterpret_cast<const uint4*>(&K[(size_t)(kb + row) * KVDIM + kvh * HEAD_D + col]);
      uint4 vv = *reinterpret_cast<const uint4*>(&V[(size_t)(kb + row) * KVDIM + kvh * HEAD_D + col]);
      u32 vw[4] = {vv.x, vv.y, vv.z, vv.w};
#pragma unroll
      for (int j = 0; j < 4; ++j) {
        Vt[(col + 2 * j) * VLD + row] = (u16)(vw[j] & 0xffff);
        Vt[(col + 2 * j + 1) * VLD + row] = (u16)(vw[j] >> 16);
      }
    }
    __syncthreads();
    if (kb <= qbase + 15) {
      // S = Q K^T for this 16q x 32k tile
      f32x4 sf[2];
#pragma unroll
      for (int nt = 0; nt < 2; ++nt) {
        f32x4 s = {0.f, 0.f, 0.f, 0.f};
#pragma unroll
        for (int c = 0; c < 4; ++c) {
          bf16x8 kf = *reinterpret_cast<const bf16x8*>(&Ks[(nt * 16 + lr) * KLD + c * 32 + lhi * 8]);
          s = __builtin_amdgcn_mfma_f32_16x16x32_bf16(qf[c], kf, s, 0, 0, 0);
        }
        sf[nt] = s;
      }
      float pm[4], fac[4], rs[4];
#pragma unroll
      for (int r = 0; r < 4; ++r) {
        int gq = qbase + lhi * 4 + r;
#pragma unroll
        for (int nt = 0; nt < 2; ++nt) {
          float sv = sf[nt][r] * scale;
          if (kb + nt * 16 + lr > gq) sv = -1e30f;
          sf[nt][r] = sv;
        }
        pm[r] = fmaxf(sf[0][r], sf[1][r]);
      }
#pragma unroll
      for (int d = 1; d < 16; d <<= 1)
#pragma unroll
        for (int r = 0; r < 4; ++r) pm[r] = fmaxf(pm[r], __shfl_xor(pm[r], d));
#pragma unroll
      for (int r = 0; r < 4; ++r) {
        float mn = fmaxf(m_[r], pm[r]);
        fac[r] = __expf(m_[r] - mn);
        m_[r] = mn;
        rs[r] = 0.f;
      }
#pragma unroll
      for (int nt = 0; nt < 2; ++nt)
#pragma unroll
        for (int r = 0; r < 4; ++r) {
          float p = __expf(sf[nt][r] - m_[r]);
          sf[nt][r] = p;
          rs[r] += p;
        }
#pragma unroll
      for (int d = 1; d < 16; d <<= 1)
#pragma unroll
        for (int r = 0; r < 4; ++r) rs[r] += __shfl_xor(rs[r], d);
#pragma unroll
      for (int r = 0; r < 4; ++r) l_[r] = l_[r] * fac[r] + rs[r];
#pragma unroll
      for (int dt = 0; dt < 8; ++dt)
#pragma unroll
        for (int r = 0; r < 4; ++r) o_[dt][r] *= fac[r];
      // P -> LDS (bf16), then PV
#pragma unroll
      for (int nt = 0; nt < 2; ++nt)
#pragma unroll
        for (int r = 0; r < 4; ++r)
          Pl[wid][(lhi * 4 + r) * PLD + nt * 16 + lr] = f2bf(sf[nt][r]);
      bf16x8 pf = *reinterpret_cast<const bf16x8*>(&Pl[wid][lr * PLD + lhi * 8]);
#pragma unroll
      for (int dt = 0; dt < 8; ++dt) {
        bf16x8 vf = *reinterpret_cast<const bf16x8*>(&Vt[(dt * 16 + lr) * VLD + lhi * 8]);
        o_[dt] = __builtin_amdgcn_mfma_f32_16x16x32_bf16(pf, vf, o_[dt], 0, 0, 0);
      }
    }
    __syncthreads();
  }
#pragma unroll
  for (int dt = 0; dt < 8; ++dt)
#pragma unroll
    for (int r = 0; r < 4; ++r) {
      float val = o_[dt][r] / l_[r];
      O[(size_t)(qbase + lhi * 4 + r) * HDIM + h * HEAD_D + dt * 16 + lr] = f2bf(val);
    }
}

extern "C" void kernel_launch(void* const* d_in, const int* in_sizes, int n_in,
                              void* d_out, int out_size, void* d_ws, size_t ws_size,
                              hipStream_t stream) {
  const float* hs = (const float*)d_in[0];
  const float* wq = (const float*)d_in[1];
  const float* wk = (const float*)d_in[2];
  const float* wv = (const float*)d_in[3];
  const float* wo = (const float*)d_in[4];

  char* ws = (char*)d_ws;
  size_t off = 0;
  auto alloc = [&](size_t bytes) {
    void* p = ws + off;
    off += (bytes + 255) & ~(size_t)255;
    return p;
  };
  u16* Xb = (u16*)alloc((size_t)S_LEN * HDIM * 2);
  u16* WqT = (u16*)alloc((size_t)HDIM * HDIM * 2);
  u16* WkT = (u16*)alloc((size_t)KVDIM * HDIM * 2);
  u16* WvT = (u16*)alloc((size_t)KVDIM * HDIM * 2);
  u16* WoT = (u16*)alloc((size_t)HDIM * HDIM * 2);
  u16* Qb = (u16*)alloc((size_t)S_LEN * HDIM * 2);
  u16* Kb = (u16*)alloc((size_t)S_LEN * KVDIM * 2);
  u16* Vb = (u16*)alloc((size_t)S_LEN * KVDIM * 2);
  u16* Ab = (u16*)alloc((size_t)S_LEN * HDIM * 2);
  float* cosT = (float*)alloc((size_t)S_LEN * 64 * 4);
  float* sinT = (float*)alloc((size_t)S_LEN * 64 * 4);
  if (off > ws_size) return;  // workspace too small; avoid OOB

  // 1. cast hidden to bf16
  k_cast_bf16<<<dim3(S_LEN * HDIM / 8 / 256), dim3(256), 0, stream>>>(hs, Xb, S_LEN * HDIM / 8);
  // 2. transpose weights to [N][K] bf16
  k_transpose_cast<<<dim3(HDIM / 32, HDIM / 32), dim3(32, 8), 0, stream>>>(wq, WqT, HDIM, HDIM);
  k_transpose_cast<<<dim3(KVDIM / 32, HDIM / 32), dim3(32, 8), 0, stream>>>(wk, WkT, HDIM, KVDIM);
  k_transpose_cast<<<dim3(KVDIM / 32, HDIM / 32), dim3(32, 8), 0, stream>>>(wv, WvT, HDIM, KVDIM);
  k_transpose_cast<<<dim3(HDIM / 32, HDIM / 32), dim3(32, 8), 0, stream>>>(wo, WoT, HDIM, HDIM);
  // 3. rope table
  k_rope_table<<<dim3(S_LEN * 64 / 256), dim3(256), 0, stream>>>(cosT, sinT);
  // 4. QKV projections
  k_gemm_bt<1><<<dim3(32, 16), dim3(256), 0, stream>>>(Xb, WqT, (void*)Qb, S_LEN, HDIM, HDIM);
  k_gemm_bt<1><<<dim3(32, 4), dim3(256), 0, stream>>>(Xb, WkT, (void*)Kb, S_LEN, KVDIM, HDIM);
  k_gemm_bt<1><<<dim3(32, 4), dim3(256), 0, stream>>>(Xb, WvT, (void*)Vb, S_LEN, KVDIM, HDIM);
  // 5. rope on Q, K
  k_rope_apply<<<dim3(S_LEN * HDIM / 8 / 256), dim3(256), 0, stream>>>(Qb, cosT, sinT, HDIM);
  k_rope_apply<<<dim3(S_LEN * KVDIM / 8 / 256), dim3(256), 0, stream>>>(Kb, cosT, sinT, KVDIM);
  // 6. attention
  k_attn<<<dim3(S_LEN / 64, N_HEADS), dim3(256), 0, stream>>>(Qb, Kb, Vb, Ab);
  // 7. output projection -> f32
  k_gemm_bt<0><<<dim3(32, 16), dim3(256), 0, stream>>>(Ab, WoT, d_out, S_LEN, HDIM, HDIM);
}

// Round 3
// 583.027 us; speedup vs baseline: 1.6553x; 1.6553x over previous
//
#include <hip/hip_runtime.h>

typedef unsigned short u16;
typedef unsigned int u32;
typedef __bf16 bf16x8 __attribute__((ext_vector_type(8)));
typedef float f32x4 __attribute__((ext_vector_type(4)));

#define S_LEN 4096
#define HDIM 2048
#define KVDIM 512
#define N_HEADS 16
#define HEAD_D 128

__device__ __forceinline__ u16 f2bf(float f) {
  u32 u = __float_as_uint(f);
  u32 r = (u + 0x7FFFu + ((u >> 16) & 1u)) >> 16;
  return (u16)r;
}
__device__ __forceinline__ float bf2f(u16 h) {
  return __uint_as_float(((u32)h) << 16);
}

// ---------------- f32 -> bf16 cast (8 elems/thread) ----------------
__global__ void k_cast_bf16(const float* __restrict__ in, u16* __restrict__ out, int n8) {
  int i = blockIdx.x * blockDim.x + threadIdx.x;
  if (i >= n8) return;
  const float4* p = reinterpret_cast<const float4*>(in) + (size_t)i * 2;
  float4 a = p[0], b = p[1];
  u32 o0 = (u32)f2bf(a.x) | ((u32)f2bf(a.y) << 16);
  u32 o1 = (u32)f2bf(a.z) | ((u32)f2bf(a.w) << 16);
  u32 o2 = (u32)f2bf(b.x) | ((u32)f2bf(b.y) << 16);
  u32 o3 = (u32)f2bf(b.z) | ((u32)f2bf(b.w) << 16);
  reinterpret_cast<uint4*>(out)[i] = make_uint4(o0, o1, o2, o3);
}

// ---------------- W [Kd][Nd] f32 -> Wt [Nd][Kd] bf16 ----------------
__global__ void k_transpose_cast(const float* __restrict__ W, u16* __restrict__ Wt,
                                 int Kd, int Nd) {
  __shared__ float t[32][33];
  int bx = blockIdx.x, by = blockIdx.y;
  int tx = threadIdx.x, ty = threadIdx.y;
  int n = bx * 32 + tx;
  for (int j = ty; j < 32; j += 8)
    t[j][tx] = W[(size_t)(by * 32 + j) * Nd + n];
  __syncthreads();
  int k = by * 32 + tx;
  for (int j = ty; j < 32; j += 8)
    Wt[(size_t)(bx * 32 + j) * Kd + k] = f2bf(t[tx][j]);
}

// ---------------- RoPE table: cos/sin [S][64] f32 ----------------
__global__ void k_rope_table(float* __restrict__ cosT, float* __restrict__ sinT) {
  int i = blockIdx.x * blockDim.x + threadIdx.x;  // S*64
  int pos = i >> 6, f = i & 63;
  float inv = expf(-0.1439115683121279f * (float)f);  // 10000^(-f/64)
  float ang = (float)pos * inv;
  float s, c;
  sincosf(ang, &s, &c);
  cosT[i] = c;
  sinT[i] = s;
}

// ---------------- interleaved RoPE in-place on bf16 [S][width] ----------------
__global__ void k_rope_apply(u16* __restrict__ X, const float* __restrict__ cosT,
                             const float* __restrict__ sinT, int width) {
  int i = blockIdx.x * blockDim.x + threadIdx.x;  // S*width/8 threads
  size_t idx = (size_t)i * 8;
  int row = (int)(idx / width);
  int col = (int)(idx - (size_t)row * width);
  int fi = (col & 127) >> 1;  // multiple of 4
  float4 c4 = *reinterpret_cast<const float4*>(&cosT[(row << 6) + fi]);
  float4 s4 = *reinterpret_cast<const float4*>(&sinT[(row << 6) + fi]);
  uint4 v = *reinterpret_cast<const uint4*>(&X[idx]);
  float cc[4] = {c4.x, c4.y, c4.z, c4.w};
  float ss[4] = {s4.x, s4.y, s4.z, s4.w};
  u32 w_[4] = {v.x, v.y, v.z, v.w};
  u32 r_[4];
#pragma unroll
  for (int p = 0; p < 4; ++p) {
    float x1 = bf2f((u16)(w_[p] & 0xffff));
    float x2 = bf2f((u16)(w_[p] >> 16));
    float r1 = x1 * cc[p] - x2 * ss[p];
    float r2 = x1 * ss[p] + x2 * cc[p];
    r_[p] = (u32)f2bf(r1) | ((u32)f2bf(r2) << 16);
  }
  *reinterpret_cast<uint4*>(&X[idx]) = make_uint4(r_[0], r_[1], r_[2], r_[3]);
}

// ---------------- GEMM: C[M][N] = A[M][K](bf16) * Bt[N][K](bf16)^T ----------------
// 128x128 tile, BK=32, 4 waves (2x2), each wave 64x64 = 4x4 MFMA 16x16x32 tiles.
// OUT_MODE: 0 = f32 C[M][N]; 1 = bf16 C[M][N]; 2 = bf16 C^T[N][M] (packed ushort4)
template <int OUT_MODE>
__global__ __launch_bounds__(256) void k_gemm_bt(
    const u16* __restrict__ A, const u16* __restrict__ Bt, void* __restrict__ Cout,
    int M, int N, int Kd) {
  constexpr int LDT = 40;  // padded k-stride (80B, 16B-aligned, bank-friendly)
  __shared__ __align__(16) u16 As[128 * LDT];
  __shared__ __align__(16) u16 Bs[128 * LDT];
  const int bm = blockIdx.x * 128;
  const int bn = blockIdx.y * 128;
  const int tid = threadIdx.x;
  const int lane = tid & 63;
  const int wid = tid >> 6;
  const int wr = (wid >> 1) * 64, wc = (wid & 1) * 64;
  const int lr = lane & 15, lhi = lane >> 4;
  f32x4 acc[4][4] = {};
  for (int k0 = 0; k0 < Kd; k0 += 32) {
#pragma unroll
    for (int it = 0; it < 2; ++it) {
      int t2 = it * 256 + tid;
      int row = t2 >> 2;
      int kc = (t2 & 3) * 8;
      *reinterpret_cast<uint4*>(&As[row * LDT + kc]) =
          *reinterpret_cast<const uint4*>(&A[(size_t)(bm + row) * Kd + k0 + kc]);
      *reinterpret_cast<uint4*>(&Bs[row * LDT + kc]) =
          *reinterpret_cast<const uint4*>(&Bt[(size_t)(bn + row) * Kd + k0 + kc]);
    }
    __syncthreads();
    bf16x8 af[4], bfr[4];
#pragma unroll
    for (int m = 0; m < 4; ++m)
      af[m] = *reinterpret_cast<const bf16x8*>(&As[(wr + m * 16 + lr) * LDT + lhi * 8]);
#pragma unroll
    for (int n = 0; n < 4; ++n)
      bfr[n] = *reinterpret_cast<const bf16x8*>(&Bs[(wc + n * 16 + lr) * LDT + lhi * 8]);
#pragma unroll
    for (int m = 0; m < 4; ++m)
#pragma unroll
      for (int n = 0; n < 4; ++n)
        acc[m][n] = __builtin_amdgcn_mfma_f32_16x16x32_bf16(af[m], bfr[n], acc[m][n], 0, 0, 0);
    __syncthreads();
  }
#pragma unroll
  for (int m = 0; m < 4; ++m) {
    int grow0 = bm + wr + m * 16 + lhi * 4;
#pragma unroll
    for (int n = 0; n < 4; ++n) {
      int gcol = bn + wc + n * 16 + lr;
      if (OUT_MODE == 2) {
        ushort4 pk;
        pk.x = f2bf(acc[m][n][0]);
        pk.y = f2bf(acc[m][n][1]);
        pk.z = f2bf(acc[m][n][2]);
        pk.w = f2bf(acc[m][n][3]);
        *reinterpret_cast<ushort4*>(
            &reinterpret_cast<u16*>(Cout)[(size_t)gcol * M + grow0]) = pk;
      } else {
#pragma unroll
        for (int r = 0; r < 4; ++r) {
          float v = acc[m][n][r];
          if (OUT_MODE == 1)
            reinterpret_cast<u16*>(Cout)[(size_t)(grow0 + r) * N + gcol] = f2bf(v);
          else
            reinterpret_cast<float*>(Cout)[(size_t)(grow0 + r) * N + gcol] = v;
        }
      }
    }
  }
}

// ---------------- flash attention v2 (causal, GQA) ----------------
// grid (64, 16), 256 threads = 4 waves; wave owns 16 q-rows; KVBLK = 64.
// qt = 63 - bx (LPT: longest blocks first). V consumed pre-transposed (VT).
__global__ __launch_bounds__(256) void k_attn(
    const u16* __restrict__ Q, const u16* __restrict__ K, const u16* __restrict__ VT,
    u16* __restrict__ O) {
  __shared__ __align__(16) u16 Ks[64 * 128];   // [kv][d], xor-swizzled, 16KB
  __shared__ __align__(16) u16 Vs[128 * 64];   // [d][kv], xor-swizzled, 16KB
  __shared__ __align__(16) u16 Pl[4][16 * 72]; // per-wave P[16q][64kv], PLD=72
  const int h = blockIdx.y;
  const int kvh = h >> 2;
  const int qt = 63 - blockIdx.x;
  const int tid = threadIdx.x, lane = tid & 63, wid = tid >> 6;
  const int lr = lane & 15, lhi = lane >> 4;
  const int qbase = qt * 64 + wid * 16;
  const float scale = 0.08838834764831845f;  // 1/sqrt(128)

  bf16x8 qf[4];
#pragma unroll
  for (int c = 0; c < 4; ++c)
    qf[c] = *reinterpret_cast<const bf16x8*>(
        &Q[(size_t)(qbase + lr) * HDIM + h * HEAD_D + c * 32 + lhi * 8]);

  f32x4 o_[8] = {};
  float m_[4] = {-3e38f, -3e38f, -3e38f, -3e38f};
  float l_[4] = {0.f, 0.f, 0.f, 0.f};
  char* KsB = (char*)Ks;
  char* VsB = (char*)Vs;
  u16* pw = Pl[wid];

  for (int j = 0; j <= qt; ++j) {
    const int kb = j << 6;
    __syncthreads();
    // stage K tile [64 kv][128 d]: 1024 uint4
#pragma unroll
    for (int it = 0; it < 4; ++it) {
      int s = it * 256 + tid;
      int kv = s >> 4, c16 = s & 15;
      int db = kv * 256 + c16 * 16;
      db ^= ((db >> 8) & 7) << 4;
      *reinterpret_cast<uint4*>(KsB + db) = *reinterpret_cast<const uint4*>(
          &K[(size_t)(kb + kv) * KVDIM + kvh * HEAD_D + c16 * 8]);
    }
    // stage V^T tile [128 d][64 kv]: 1024 uint4
#pragma unroll
    for (int it = 0; it < 4; ++it) {
      int s = it * 256 + tid;
      int d = s >> 3, k16 = s & 7;
      int db = d * 128 + k16 * 16;
      db ^= ((db >> 7) & 7) << 4;
      *reinterpret_cast<uint4*>(VsB + db) = *reinterpret_cast<const uint4*>(
          &VT[(size_t)(kvh * HEAD_D + d) * S_LEN + kb + k16 * 8]);
    }
    __syncthreads();

    // QK^T: S[16q][64kv]
    f32x4 sf[4];
#pragma unroll
    for (int nt = 0; nt < 4; ++nt) {
      f32x4 s = {0.f, 0.f, 0.f, 0.f};
#pragma unroll
      for (int c = 0; c < 4; ++c) {
        int db = (nt * 16 + lr) * 256 + c * 64 + lhi * 16;
        db ^= ((db >> 8) & 7) << 4;
        bf16x8 kf = *reinterpret_cast<const bf16x8*>(KsB + db);
        s = __builtin_amdgcn_mfma_f32_16x16x32_bf16(qf[c], kf, s, 0, 0, 0);
      }
      sf[nt] = s;
    }
    // scale + causal mask (diagonal tile only)
    const bool diag = (j == qt);
#pragma unroll
    for (int nt = 0; nt < 4; ++nt)
#pragma unroll
      for (int r = 0; r < 4; ++r) {
        float sv = sf[nt][r] * scale;
        if (diag && (kb + nt * 16 + lr > qbase + lhi * 4 + r)) sv = -1e30f;
        sf[nt][r] = sv;
      }
    // online softmax over 64 kv
    float pm[4];
#pragma unroll
    for (int r = 0; r < 4; ++r)
      pm[r] = fmaxf(fmaxf(sf[0][r], sf[1][r]), fmaxf(sf[2][r], sf[3][r]));
#pragma unroll
    for (int d = 1; d < 16; d <<= 1)
#pragma unroll
      for (int r = 0; r < 4; ++r) pm[r] = fmaxf(pm[r], __shfl_xor(pm[r], d));
    float fac[4], rs[4];
#pragma unroll
    for (int r = 0; r < 4; ++r) {
      float mn = fmaxf(m_[r], pm[r]);
      fac[r] = __expf(m_[r] - mn);
      m_[r] = mn;
      rs[r] = 0.f;
    }
#pragma unroll
    for (int nt = 0; nt < 4; ++nt)
#pragma unroll
      for (int r = 0; r < 4; ++r) {
        float p = __expf(sf[nt][r] - m_[r]);
        sf[nt][r] = p;
        rs[r] += p;
      }
#pragma unroll
    for (int d = 1; d < 16; d <<= 1)
#pragma unroll
      for (int r = 0; r < 4; ++r) rs[r] += __shfl_xor(rs[r], d);
#pragma unroll
    for (int r = 0; r < 4; ++r) l_[r] = l_[r] * fac[r] + rs[r];
#pragma unroll
    for (int dt = 0; dt < 8; ++dt)
#pragma unroll
      for (int r = 0; r < 4; ++r) o_[dt][r] *= fac[r];
    // P -> per-wave LDS (bf16)
#pragma unroll
    for (int nt = 0; nt < 4; ++nt)
#pragma unroll
      for (int r = 0; r < 4; ++r)
        pw[(lhi * 4 + r) * 72 + nt * 16 + lr] = f2bf(sf[nt][r]);
    // PV: O[16q][128d] += P[16q][64kv] * V[64kv][128d]
#pragma unroll
    for (int kk = 0; kk < 2; ++kk) {
      bf16x8 pa = *reinterpret_cast<const bf16x8*>(&pw[lr * 72 + kk * 32 + lhi * 8]);
#pragma unroll
      for (int dt = 0; dt < 8; ++dt) {
        int db = (dt * 16 + lr) * 128 + kk * 64 + lhi * 16;
        db ^= ((db >> 7) & 7) << 4;
        bf16x8 vf = *reinterpret_cast<const bf16x8*>(VsB + db);
        o_[dt] = __builtin_amdgcn_mfma_f32_16x16x32_bf16(pa, vf, o_[dt], 0, 0, 0);
      }
    }
  }
#pragma unroll
  for (int dt = 0; dt < 8; ++dt)
#pragma unroll
    for (int r = 0; r < 4; ++r) {
      float val = o_[dt][r] / l_[r];
      O[(size_t)(qbase + lhi * 4 + r) * HDIM + h * HEAD_D + dt * 16 + lr] = f2bf(val);
    }
}

extern "C" void kernel_launch(void* const* d_in, const int* in_sizes, int n_in,
                              void* d_out, int out_size, void* d_ws, size_t ws_size,
                              hipStream_t stream) {
  const float* hs = (const float*)d_in[0];
  const float* wq = (const float*)d_in[1];
  const float* wk = (const float*)d_in[2];
  const float* wv = (const float*)d_in[3];
  const float* wo = (const float*)d_in[4];

  char* ws = (char*)d_ws;
  size_t off = 0;
  auto alloc = [&](size_t bytes) {
    void* p = ws + off;
    off += (bytes + 255) & ~(size_t)255;
    return p;
  };
  u16* Xb = (u16*)alloc((size_t)S_LEN * HDIM * 2);
  u16* WqT = (u16*)alloc((size_t)HDIM * HDIM * 2);
  u16* WkT = (u16*)alloc((size_t)KVDIM * HDIM * 2);
  u16* WvT = (u16*)alloc((size_t)KVDIM * HDIM * 2);
  u16* WoT = (u16*)alloc((size_t)HDIM * HDIM * 2);
  u16* Qb = (u16*)alloc((size_t)S_LEN * HDIM * 2);
  u16* Kb = (u16*)alloc((size_t)S_LEN * KVDIM * 2);
  u16* VTb = (u16*)alloc((size_t)KVDIM * S_LEN * 2);  // V^T [512][4096]
  u16* Ab = (u16*)alloc((size_t)S_LEN * HDIM * 2);
  float* cosT = (float*)alloc((size_t)S_LEN * 64 * 4);
  float* sinT = (float*)alloc((size_t)S_LEN * 64 * 4);
  if (off > ws_size) return;  // workspace too small; avoid OOB

  // 1. cast hidden to bf16
  k_cast_bf16<<<dim3(S_LEN * HDIM / 8 / 256), dim3(256), 0, stream>>>(hs, Xb, S_LEN * HDIM / 8);
  // 2. transpose weights to [N][K] bf16
  k_transpose_cast<<<dim3(HDIM / 32, HDIM / 32), dim3(32, 8), 0, stream>>>(wq, WqT, HDIM, HDIM);
  k_transpose_cast<<<dim3(KVDIM / 32, HDIM / 32), dim3(32, 8), 0, stream>>>(wk, WkT, HDIM, KVDIM);
  k_transpose_cast<<<dim3(KVDIM / 32, HDIM / 32), dim3(32, 8), 0, stream>>>(wv, WvT, HDIM, KVDIM);
  k_transpose_cast<<<dim3(HDIM / 32, HDIM / 32), dim3(32, 8), 0, stream>>>(wo, WoT, HDIM, HDIM);
  // 3. rope table
  k_rope_table<<<dim3(S_LEN * 64 / 256), dim3(256), 0, stream>>>(cosT, sinT);
  // 4. QKV projections (V written transposed)
  k_gemm_bt<1><<<dim3(32, 16), dim3(256), 0, stream>>>(Xb, WqT, (void*)Qb, S_LEN, HDIM, HDIM);
  k_gemm_bt<1><<<dim3(32, 4), dim3(256), 0, stream>>>(Xb, WkT, (void*)Kb, S_LEN, KVDIM, HDIM);
  k_gemm_bt<2><<<dim3(32, 4), dim3(256), 0, stream>>>(Xb, WvT, (void*)VTb, S_LEN, KVDIM, HDIM);
  // 5. rope on Q, K
  k_rope_apply<<<dim3(S_LEN * HDIM / 8 / 256), dim3(256), 0, stream>>>(Qb, cosT, sinT, HDIM);
  k_rope_apply<<<dim3(S_LEN * KVDIM / 8 / 256), dim3(256), 0, stream>>>(Kb, cosT, sinT, KVDIM);
  // 6. attention
  k_attn<<<dim3(64, N_HEADS), dim3(256), 0, stream>>>(Qb, Kb, VTb, Ab);
  // 7. output projection -> f32
  k_gemm_bt<0><<<dim3(32, 16), dim3(256), 0, stream>>>(Ab, WoT, d_out, S_LEN, HDIM, HDIM);
}

// Round 4
// 484.685 us; speedup vs baseline: 1.9912x; 1.2029x over previous
//
#include <hip/hip_runtime.h>

typedef unsigned short u16;
typedef unsigned int u32;
typedef __bf16 bf16x8 __attribute__((ext_vector_type(8)));
typedef float f32x4 __attribute__((ext_vector_type(4)));

#define S_LEN 4096
#define HDIM 2048
#define KVDIM 512
#define N_HEADS 16
#define HEAD_D 128

__device__ __forceinline__ u16 f2bf(float f) {
  u32 u = __float_as_uint(f);
  u32 r = (u + 0x7FFFu + ((u >> 16) & 1u)) >> 16;
  return (u16)r;
}
__device__ __forceinline__ float bf2f(u16 h) {
  return __uint_as_float(((u32)h) << 16);
}
__device__ __forceinline__ float exp2_fast(float x) {
  float r;
  asm("v_exp_f32 %0, %1" : "=v"(r) : "v"(x));
  return r;
}
__device__ __forceinline__ u32 cvt_pk_bf16(float lo, float hi) {
  u32 r;
  asm("v_cvt_pk_bf16_f32 %0, %1, %2" : "=v"(r) : "v"(lo), "v"(hi));
  return r;
}

// ---------------- f32 -> bf16 cast (8 elems/thread) ----------------
__global__ void k_cast_bf16(const float* __restrict__ in, u16* __restrict__ out, int n8) {
  int i = blockIdx.x * blockDim.x + threadIdx.x;
  if (i >= n8) return;
  const float4* p = reinterpret_cast<const float4*>(in) + (size_t)i * 2;
  float4 a = p[0], b = p[1];
  u32 o0 = (u32)f2bf(a.x) | ((u32)f2bf(a.y) << 16);
  u32 o1 = (u32)f2bf(a.z) | ((u32)f2bf(a.w) << 16);
  u32 o2 = (u32)f2bf(b.x) | ((u32)f2bf(b.y) << 16);
  u32 o3 = (u32)f2bf(b.z) | ((u32)f2bf(b.w) << 16);
  reinterpret_cast<uint4*>(out)[i] = make_uint4(o0, o1, o2, o3);
}

// ---------------- W [Kd][Nd] f32 -> Wt [Nd][Kd] bf16 ----------------
__global__ void k_transpose_cast(const float* __restrict__ W, u16* __restrict__ Wt,
                                 int Kd, int Nd) {
  __shared__ float t[32][33];
  int bx = blockIdx.x, by = blockIdx.y;
  int tx = threadIdx.x, ty = threadIdx.y;
  int n = bx * 32 + tx;
  for (int j = ty; j < 32; j += 8)
    t[j][tx] = W[(size_t)(by * 32 + j) * Nd + n];
  __syncthreads();
  int k = by * 32 + tx;
  for (int j = ty; j < 32; j += 8)
    Wt[(size_t)(bx * 32 + j) * Kd + k] = f2bf(t[tx][j]);
}

// ---------------- RoPE table: cos/sin [S][64] f32 ----------------
__global__ void k_rope_table(float* __restrict__ cosT, float* __restrict__ sinT) {
  int i = blockIdx.x * blockDim.x + threadIdx.x;  // S*64
  int pos = i >> 6, f = i & 63;
  float inv = expf(-0.1439115683121279f * (float)f);  // 10000^(-f/64)
  float ang = (float)pos * inv;
  float s, c;
  sincosf(ang, &s, &c);
  cosT[i] = c;
  sinT[i] = s;
}

// ---------------- interleaved RoPE in-place on bf16 [S][width] ----------------
__global__ void k_rope_apply(u16* __restrict__ X, const float* __restrict__ cosT,
                             const float* __restrict__ sinT, int width) {
  int i = blockIdx.x * blockDim.x + threadIdx.x;  // S*width/8 threads
  size_t idx = (size_t)i * 8;
  int row = (int)(idx / width);
  int col = (int)(idx - (size_t)row * width);
  int fi = (col & 127) >> 1;  // multiple of 4
  float4 c4 = *reinterpret_cast<const float4*>(&cosT[(row << 6) + fi]);
  float4 s4 = *reinterpret_cast<const float4*>(&sinT[(row << 6) + fi]);
  uint4 v = *reinterpret_cast<const uint4*>(&X[idx]);
  float cc[4] = {c4.x, c4.y, c4.z, c4.w};
  float ss[4] = {s4.x, s4.y, s4.z, s4.w};
  u32 w_[4] = {v.x, v.y, v.z, v.w};
  u32 r_[4];
#pragma unroll
  for (int p = 0; p < 4; ++p) {
    float x1 = bf2f((u16)(w_[p] & 0xffff));
    float x2 = bf2f((u16)(w_[p] >> 16));
    float r1 = x1 * cc[p] - x2 * ss[p];
    float r2 = x1 * ss[p] + x2 * cc[p];
    r_[p] = (u32)f2bf(r1) | ((u32)f2bf(r2) << 16);
  }
  *reinterpret_cast<uint4*>(&X[idx]) = make_uint4(r_[0], r_[1], r_[2], r_[3]);
}

// ---------------- GEMM: C[M][N] = A[M][K](bf16) * Bt[N][K](bf16)^T ----------------
// 128x128 tile, BK=32, 4 waves (2x2), each wave 64x64 = 4x4 MFMA 16x16x32 tiles.
// OUT_MODE: 0 = f32 C[M][N]; 1 = bf16 C[M][N]; 2 = bf16 C^T[N][M] (packed ushort4)
template <int OUT_MODE>
__global__ __launch_bounds__(256) void k_gemm_bt(
    const u16* __restrict__ A, const u16* __restrict__ Bt, void* __restrict__ Cout,
    int M, int N, int Kd) {
  constexpr int LDT = 40;  // padded k-stride (80B, 16B-aligned, bank-friendly)
  __shared__ __align__(16) u16 As[128 * LDT];
  __shared__ __align__(16) u16 Bs[128 * LDT];
  const int bm = blockIdx.x * 128;
  const int bn = blockIdx.y * 128;
  const int tid = threadIdx.x;
  const int lane = tid & 63;
  const int wid = tid >> 6;
  const int wr = (wid >> 1) * 64, wc = (wid & 1) * 64;
  const int lr = lane & 15, lhi = lane >> 4;
  f32x4 acc[4][4] = {};
  for (int k0 = 0; k0 < Kd; k0 += 32) {
#pragma unroll
    for (int it = 0; it < 2; ++it) {
      int t2 = it * 256 + tid;
      int row = t2 >> 2;
      int kc = (t2 & 3) * 8;
      *reinterpret_cast<uint4*>(&As[row * LDT + kc]) =
          *reinterpret_cast<const uint4*>(&A[(size_t)(bm + row) * Kd + k0 + kc]);
      *reinterpret_cast<uint4*>(&Bs[row * LDT + kc]) =
          *reinterpret_cast<const uint4*>(&Bt[(size_t)(bn + row) * Kd + k0 + kc]);
    }
    __syncthreads();
    bf16x8 af[4], bfr[4];
#pragma unroll
    for (int m = 0; m < 4; ++m)
      af[m] = *reinterpret_cast<const bf16x8*>(&As[(wr + m * 16 + lr) * LDT + lhi * 8]);
#pragma unroll
    for (int n = 0; n < 4; ++n)
      bfr[n] = *reinterpret_cast<const bf16x8*>(&Bs[(wc + n * 16 + lr) * LDT + lhi * 8]);
#pragma unroll
    for (int m = 0; m < 4; ++m)
#pragma unroll
      for (int n = 0; n < 4; ++n)
        acc[m][n] = __builtin_amdgcn_mfma_f32_16x16x32_bf16(af[m], bfr[n], acc[m][n], 0, 0, 0);
    __syncthreads();
  }
#pragma unroll
  for (int m = 0; m < 4; ++m) {
    int grow0 = bm + wr + m * 16 + lhi * 4;
#pragma unroll
    for (int n = 0; n < 4; ++n) {
      int gcol = bn + wc + n * 16 + lr;
      if (OUT_MODE == 2) {
        ushort4 pk;
        pk.x = f2bf(acc[m][n][0]);
        pk.y = f2bf(acc[m][n][1]);
        pk.z = f2bf(acc[m][n][2]);
        pk.w = f2bf(acc[m][n][3]);
        *reinterpret_cast<ushort4*>(
            &reinterpret_cast<u16*>(Cout)[(size_t)gcol * M + grow0]) = pk;
      } else {
#pragma unroll
        for (int r = 0; r < 4; ++r) {
          float v = acc[m][n][r];
          if (OUT_MODE == 1)
            reinterpret_cast<u16*>(Cout)[(size_t)(grow0 + r) * N + gcol] = f2bf(v);
          else
            reinterpret_cast<float*>(Cout)[(size_t)(grow0 + r) * N + gcol] = v;
        }
      }
    }
  }
}

// ---------------- flash attention v3 (causal, GQA, swapped-operand) ----------------
// grid (64, 16), 256 threads = 4 waves; wave owns 16 q-rows; KVBLK = 64.
// qt = 63 - bx (LPT). Swapped QK^T (mfma(K,Q)) -> lane holds full score row for
// q = lr: in-lane softmax reduction + 2 shfl. Swapped PV (mfma(V^T,P)) -> O^T
// accumulator, per-lane scalar m/l/fac. V consumed pre-transposed (VT).
__global__ __launch_bounds__(256) void k_attn(
    const u16* __restrict__ Q, const u16* __restrict__ K, const u16* __restrict__ VT,
    u16* __restrict__ O) {
  __shared__ __align__(16) u16 Ks[64 * 128];    // [kv][d], xor-swizzled, 16KB
  __shared__ __align__(16) u16 Vs[128 * 64];    // [d][kv], xor-swizzled, 16KB
  __shared__ __align__(16) u16 Pl[4][16 * 72];  // per-wave P[16q][64kv], PLD=72
  const int h = blockIdx.y;
  const int kvh = h >> 2;
  const int qt = 63 - blockIdx.x;
  const int tid = threadIdx.x, lane = tid & 63, wid = tid >> 6;
  const int lr = lane & 15, lhi = lane >> 4;
  const int qbase = qt * 64 + wid * 16;
  const int qglob = qbase + lr;
  const float CE = 0.12751743f;  // log2(e)/sqrt(128)

  bf16x8 qf[4];
#pragma unroll
  for (int c = 0; c < 4; ++c)
    qf[c] = *reinterpret_cast<const bf16x8*>(
        &Q[(size_t)(qbase + lr) * HDIM + h * HEAD_D + c * 32 + lhi * 8]);

  f32x4 o_[8] = {};
  float m_ = -3e38f, l_ = 0.f;
  char* KsB = (char*)Ks;
  char* VsB = (char*)Vs;
  u16* pw = Pl[wid];

  for (int j = 0; j <= qt; ++j) {
    const int kb = j << 6;
    __syncthreads();
    // stage K tile [64 kv][128 d]: 1024 uint4
#pragma unroll
    for (int it = 0; it < 4; ++it) {
      int s = it * 256 + tid;
      int kv = s >> 4, c16 = s & 15;
      int db = kv * 256 + c16 * 16;
      db ^= ((db >> 8) & 7) << 4;
      *reinterpret_cast<uint4*>(KsB + db) = *reinterpret_cast<const uint4*>(
          &K[(size_t)(kb + kv) * KVDIM + kvh * HEAD_D + c16 * 8]);
    }
    // stage V^T tile [128 d][64 kv]: 1024 uint4
#pragma unroll
    for (int it = 0; it < 4; ++it) {
      int s = it * 256 + tid;
      int d = s >> 3, k16 = s & 7;
      int db = d * 128 + k16 * 16;
      db ^= ((db >> 7) & 7) << 4;
      *reinterpret_cast<uint4*>(VsB + db) = *reinterpret_cast<const uint4*>(
          &VT[(size_t)(kvh * HEAD_D + d) * S_LEN + kb + k16 * 8]);
    }
    __syncthreads();

    // QK^T swapped: lane holds S^T[kv][q]: q = lr, kv = kb + nt*16 + lhi*4 + r
    f32x4 sf[4];
#pragma unroll
    for (int nt = 0; nt < 4; ++nt) {
      f32x4 s = {0.f, 0.f, 0.f, 0.f};
#pragma unroll
      for (int c = 0; c < 4; ++c) {
        int db = (nt * 16 + lr) * 256 + c * 64 + lhi * 16;
        db ^= ((db >> 8) & 7) << 4;
        bf16x8 kf = *reinterpret_cast<const bf16x8*>(KsB + db);
        s = __builtin_amdgcn_mfma_f32_16x16x32_bf16(kf, qf[c], s, 0, 0, 0);
      }
      sf[nt] = s;
    }
    // causal mask: diagonal tile only (wave-uniform branch)
    if (j == qt) {
#pragma unroll
      for (int nt = 0; nt < 4; ++nt)
#pragma unroll
        for (int r = 0; r < 4; ++r)
          if (kb + nt * 16 + lhi * 4 + r > qglob) sf[nt][r] = -1e30f;
    }
    // row max: in-lane over 16 + 2 shfl
    float pm = sf[0][0];
#pragma unroll
    for (int nt = 0; nt < 4; ++nt)
#pragma unroll
      for (int r = 0; r < 4; ++r) pm = fmaxf(pm, sf[nt][r]);
    pm = fmaxf(pm, __shfl_xor(pm, 16));
    pm = fmaxf(pm, __shfl_xor(pm, 32));
    float mnew = fmaxf(m_, pm);
    float fac = exp2_fast((m_ - mnew) * CE);
    m_ = mnew;
    const float mc = mnew * CE;
    // p = exp2(s*CE - mc); pack to bf16 pairs; in-lane sum
    float rs = 0.f;
    u32 pkw[8];
#pragma unroll
    for (int nt = 0; nt < 4; ++nt) {
      float p0 = exp2_fast(__builtin_fmaf(sf[nt][0], CE, -mc));
      float p1 = exp2_fast(__builtin_fmaf(sf[nt][1], CE, -mc));
      float p2 = exp2_fast(__builtin_fmaf(sf[nt][2], CE, -mc));
      float p3 = exp2_fast(__builtin_fmaf(sf[nt][3], CE, -mc));
      rs += (p0 + p1) + (p2 + p3);
      pkw[2 * nt] = cvt_pk_bf16(p0, p1);
      pkw[2 * nt + 1] = cvt_pk_bf16(p2, p3);
    }
    rs += __shfl_xor(rs, 16);
    rs += __shfl_xor(rs, 32);
    l_ = l_ * fac + rs;
    // P^T -> per-wave LDS: row q=lr, cols kv; 4x ds_write_b64
#pragma unroll
    for (int nt = 0; nt < 4; ++nt) {
      uint2 w2 = make_uint2(pkw[2 * nt], pkw[2 * nt + 1]);
      *reinterpret_cast<uint2*>(&pw[lr * 72 + nt * 16 + lhi * 4]) = w2;
    }
    // rescale O^T (scalar fac per lane)
#pragma unroll
    for (int dt = 0; dt < 8; ++dt)
#pragma unroll
      for (int r = 0; r < 4; ++r) o_[dt][r] *= fac;
    // PV swapped: O^T[d][q] += V^T[d][kv] * P^T[kv][q]
#pragma unroll
    for (int kk = 0; kk < 2; ++kk) {
      bf16x8 pb = *reinterpret_cast<const bf16x8*>(&pw[lr * 72 + kk * 32 + lhi * 8]);
#pragma unroll
      for (int dt = 0; dt < 8; ++dt) {
        int db = (dt * 16 + lr) * 128 + kk * 64 + lhi * 16;
        db ^= ((db >> 7) & 7) << 4;
        bf16x8 vf = *reinterpret_cast<const bf16x8*>(VsB + db);
        o_[dt] = __builtin_amdgcn_mfma_f32_16x16x32_bf16(vf, pb, o_[dt], 0, 0, 0);
      }
    }
  }
  // O^T layout: lane holds O[q = qbase+lr][d = dt*16 + lhi*4 + r]
  const float inv_l = 1.0f / l_;
#pragma unroll
  for (int dt = 0; dt < 8; ++dt) {
    ushort4 pk;
    pk.x = f2bf(o_[dt][0] * inv_l);
    pk.y = f2bf(o_[dt][1] * inv_l);
    pk.z = f2bf(o_[dt][2] * inv_l);
    pk.w = f2bf(o_[dt][3] * inv_l);
    *reinterpret_cast<ushort4*>(
        &O[(size_t)(qbase + lr) * HDIM + h * HEAD_D + dt * 16 + lhi * 4]) = pk;
  }
}

extern "C" void kernel_launch(void* const* d_in, const int* in_sizes, int n_in,
                              void* d_out, int out_size, void* d_ws, size_t ws_size,
                              hipStream_t stream) {
  const float* hs = (const float*)d_in[0];
  const float* wq = (const float*)d_in[1];
  const float* wk = (const float*)d_in[2];
  const float* wv = (const float*)d_in[3];
  const float* wo = (const float*)d_in[4];

  char* ws = (char*)d_ws;
  size_t off = 0;
  auto alloc = [&](size_t bytes) {
    void* p = ws + off;
    off += (bytes + 255) & ~(size_t)255;
    return p;
  };
  u16* Xb = (u16*)alloc((size_t)S_LEN * HDIM * 2);
  u16* WqT = (u16*)alloc((size_t)HDIM * HDIM * 2);
  u16* WkT = (u16*)alloc((size_t)KVDIM * HDIM * 2);
  u16* WvT = (u16*)alloc((size_t)KVDIM * HDIM * 2);
  u16* WoT = (u16*)alloc((size_t)HDIM * HDIM * 2);
  u16* Qb = (u16*)alloc((size_t)S_LEN * HDIM * 2);
  u16* Kb = (u16*)alloc((size_t)S_LEN * KVDIM * 2);
  u16* VTb = (u16*)alloc((size_t)KVDIM * S_LEN * 2);  // V^T [512][4096]
  u16* Ab = (u16*)alloc((size_t)S_LEN * HDIM * 2);
  float* cosT = (float*)alloc((size_t)S_LEN * 64 * 4);
  float* sinT = (float*)alloc((size_t)S_LEN * 64 * 4);
  if (off > ws_size) return;  // workspace too small; avoid OOB

  // 1. cast hidden to bf16
  k_cast_bf16<<<dim3(S_LEN * HDIM / 8 / 256), dim3(256), 0, stream>>>(hs, Xb, S_LEN * HDIM / 8);
  // 2. transpose weights to [N][K] bf16
  k_transpose_cast<<<dim3(HDIM / 32, HDIM / 32), dim3(32, 8), 0, stream>>>(wq, WqT, HDIM, HDIM);
  k_transpose_cast<<<dim3(KVDIM / 32, HDIM / 32), dim3(32, 8), 0, stream>>>(wk, WkT, HDIM, KVDIM);
  k_transpose_cast<<<dim3(KVDIM / 32, HDIM / 32), dim3(32, 8), 0, stream>>>(wv, WvT, HDIM, KVDIM);
  k_transpose_cast<<<dim3(HDIM / 32, HDIM / 32), dim3(32, 8), 0, stream>>>(wo, WoT, HDIM, HDIM);
  // 3. rope table
  k_rope_table<<<dim3(S_LEN * 64 / 256), dim3(256), 0, stream>>>(cosT, sinT);
  // 4. QKV projections (V written transposed)
  k_gemm_bt<1><<<dim3(32, 16), dim3(256), 0, stream>>>(Xb, WqT, (void*)Qb, S_LEN, HDIM, HDIM);
  k_gemm_bt<1><<<dim3(32, 4), dim3(256), 0, stream>>>(Xb, WkT, (void*)Kb, S_LEN, KVDIM, HDIM);
  k_gemm_bt<2><<<dim3(32, 4), dim3(256), 0, stream>>>(Xb, WvT, (void*)VTb, S_LEN, KVDIM, HDIM);
  // 5. rope on Q, K
  k_rope_apply<<<dim3(S_LEN * HDIM / 8 / 256), dim3(256), 0, stream>>>(Qb, cosT, sinT, HDIM);
  k_rope_apply<<<dim3(S_LEN * KVDIM / 8 / 256), dim3(256), 0, stream>>>(Kb, cosT, sinT, KVDIM);
  // 6. attention
  k_attn<<<dim3(64, N_HEADS), dim3(256), 0, stream>>>(Qb, Kb, VTb, Ab);
  // 7. output projection -> f32
  k_gemm_bt<0><<<dim3(32, 16), dim3(256), 0, stream>>>(Ab, WoT, d_out, S_LEN, HDIM, HDIM);
}

// Round 5
// 410.052 us; speedup vs baseline: 2.3536x; 1.1820x over previous
//
#include <hip/hip_runtime.h>

typedef unsigned short u16;
typedef unsigned int u32;
typedef __bf16 bf16x8 __attribute__((ext_vector_type(8)));
typedef float f32x4 __attribute__((ext_vector_type(4)));

#define S_LEN 4096
#define HDIM 2048
#define KVDIM 512
#define N_HEADS 16
#define HEAD_D 128

__device__ __forceinline__ u16 f2bf(float f) {
  u32 u = __float_as_uint(f);
  u32 r = (u + 0x7FFFu + ((u >> 16) & 1u)) >> 16;
  return (u16)r;
}
__device__ __forceinline__ float bf2f(u16 h) {
  return __uint_as_float(((u32)h) << 16);
}
__device__ __forceinline__ float exp2_fast(float x) {
  float r;
  asm("v_exp_f32 %0, %1" : "=v"(r) : "v"(x));
  return r;
}
__device__ __forceinline__ u32 cvt_pk_bf16(float lo, float hi) {
  u32 r;
  asm("v_cvt_pk_bf16_f32 %0, %1, %2" : "=v"(r) : "v"(lo), "v"(hi));
  return r;
}
__device__ __forceinline__ void gload16(const u16* g, u16* l) {
  __builtin_amdgcn_global_load_lds(
      (const __attribute__((address_space(1))) void*)g,
      (__attribute__((address_space(3))) void*)l, 16, 0, 0);
}

// ---------------- f32 -> bf16 cast (8 elems/thread) ----------------
__global__ void k_cast_bf16(const float* __restrict__ in, u16* __restrict__ out, int n8) {
  int i = blockIdx.x * blockDim.x + threadIdx.x;
  if (i >= n8) return;
  const float4* p = reinterpret_cast<const float4*>(in) + (size_t)i * 2;
  float4 a = p[0], b = p[1];
  u32 o0 = (u32)f2bf(a.x) | ((u32)f2bf(a.y) << 16);
  u32 o1 = (u32)f2bf(a.z) | ((u32)f2bf(a.w) << 16);
  u32 o2 = (u32)f2bf(b.x) | ((u32)f2bf(b.y) << 16);
  u32 o3 = (u32)f2bf(b.z) | ((u32)f2bf(b.w) << 16);
  reinterpret_cast<uint4*>(out)[i] = make_uint4(o0, o1, o2, o3);
}

// ---------------- W [Kd][Nd] f32 -> Wt [Nd][Kd] bf16 ----------------
__global__ void k_transpose_cast(const float* __restrict__ W, u16* __restrict__ Wt,
                                 int Kd, int Nd) {
  __shared__ float t[32][33];
  int bx = blockIdx.x, by = blockIdx.y;
  int tx = threadIdx.x, ty = threadIdx.y;
  int n = bx * 32 + tx;
  for (int j = ty; j < 32; j += 8)
    t[j][tx] = W[(size_t)(by * 32 + j) * Nd + n];
  __syncthreads();
  int k = by * 32 + tx;
  for (int j = ty; j < 32; j += 8)
    Wt[(size_t)(bx * 32 + j) * Kd + k] = f2bf(t[tx][j]);
}

// ---------------- RoPE table: cos/sin [S][64] f32 ----------------
__global__ void k_rope_table(float* __restrict__ cosT, float* __restrict__ sinT) {
  int i = blockIdx.x * blockDim.x + threadIdx.x;  // S*64
  int pos = i >> 6, f = i & 63;
  float inv = expf(-0.1439115683121279f * (float)f);  // 10000^(-f/64)
  float ang = (float)pos * inv;
  float s, c;
  sincosf(ang, &s, &c);
  cosT[i] = c;
  sinT[i] = s;
}

// ---------------- interleaved RoPE in-place on bf16 [S][width] ----------------
__global__ void k_rope_apply(u16* __restrict__ X, const float* __restrict__ cosT,
                             const float* __restrict__ sinT, int width) {
  int i = blockIdx.x * blockDim.x + threadIdx.x;  // S*width/8 threads
  size_t idx = (size_t)i * 8;
  int row = (int)(idx / width);
  int col = (int)(idx - (size_t)row * width);
  int fi = (col & 127) >> 1;  // multiple of 4
  float4 c4 = *reinterpret_cast<const float4*>(&cosT[(row << 6) + fi]);
  float4 s4 = *reinterpret_cast<const float4*>(&sinT[(row << 6) + fi]);
  uint4 v = *reinterpret_cast<const uint4*>(&X[idx]);
  float cc[4] = {c4.x, c4.y, c4.z, c4.w};
  float ss[4] = {s4.x, s4.y, s4.z, s4.w};
  u32 w_[4] = {v.x, v.y, v.z, v.w};
  u32 r_[4];
#pragma unroll
  for (int p = 0; p < 4; ++p) {
    float x1 = bf2f((u16)(w_[p] & 0xffff));
    float x2 = bf2f((u16)(w_[p] >> 16));
    float r1 = x1 * cc[p] - x2 * ss[p];
    float r2 = x1 * ss[p] + x2 * cc[p];
    r_[p] = (u32)f2bf(r1) | ((u32)f2bf(r2) << 16);
  }
  *reinterpret_cast<uint4*>(&X[idx]) = make_uint4(r_[0], r_[1], r_[2], r_[3]);
}

// ---------------- GEMM: C[M][N] = A[M][K](bf16) * Bt[N][K](bf16)^T ----------------
// m97 structure: 128x128 tile, BK=32, linear LDS [128][32], global_load_lds w=16.
// 4 waves (2x2), each wave 64x64 = 4x4 MFMA 16x16x32 tiles.
// OUT_MODE: 0 = f32 C[M][N]; 1 = bf16 C[M][N]; 2 = bf16 C^T[N][M] (packed ushort4)
template <int OUT_MODE>
__global__ __launch_bounds__(256) void k_gemm_bt(
    const u16* __restrict__ A, const u16* __restrict__ Bt, void* __restrict__ Cout,
    int M, int N, int Kd) {
  __shared__ __align__(16) u16 As[128 * 32];
  __shared__ __align__(16) u16 Bs[128 * 32];
  const int bm = blockIdx.x * 128;
  const int bn = blockIdx.y * 128;
  const int tid = threadIdx.x;
  const int lane = tid & 63;
  const int wid = tid >> 6;
  const int wr = (wid >> 1) * 64, wc = (wid & 1) * 64;
  const int lr = lane & 15, lhi = lane >> 4;
  const int srow = lane >> 2;          // 0..15 within 16-row chunk
  const int skc = (lane & 3) * 8;      // 0,8,16,24
  f32x4 acc[4][4] = {};
  for (int k0 = 0; k0 < Kd; k0 += 32) {
#pragma unroll
    for (int it = 0; it < 2; ++it) {
      int rowbase = (it * 4 + wid) * 16;
      gload16(&A[(size_t)(bm + rowbase + srow) * Kd + k0 + skc], &As[rowbase * 32]);
      gload16(&Bt[(size_t)(bn + rowbase + srow) * Kd + k0 + skc], &Bs[rowbase * 32]);
    }
    __syncthreads();
    bf16x8 af[4], bfr[4];
#pragma unroll
    for (int m = 0; m < 4; ++m)
      af[m] = *reinterpret_cast<const bf16x8*>(&As[(wr + m * 16 + lr) * 32 + lhi * 8]);
#pragma unroll
    for (int n = 0; n < 4; ++n)
      bfr[n] = *reinterpret_cast<const bf16x8*>(&Bs[(wc + n * 16 + lr) * 32 + lhi * 8]);
#pragma unroll
    for (int m = 0; m < 4; ++m)
#pragma unroll
      for (int n = 0; n < 4; ++n)
        acc[m][n] = __builtin_amdgcn_mfma_f32_16x16x32_bf16(af[m], bfr[n], acc[m][n], 0, 0, 0);
    __syncthreads();
  }
#pragma unroll
  for (int m = 0; m < 4; ++m) {
    int grow0 = bm + wr + m * 16 + lhi * 4;
#pragma unroll
    for (int n = 0; n < 4; ++n) {
      int gcol = bn + wc + n * 16 + lr;
      if (OUT_MODE == 2) {
        ushort4 pk;
        pk.x = f2bf(acc[m][n][0]);
        pk.y = f2bf(acc[m][n][1]);
        pk.z = f2bf(acc[m][n][2]);
        pk.w = f2bf(acc[m][n][3]);
        *reinterpret_cast<ushort4*>(
            &reinterpret_cast<u16*>(Cout)[(size_t)gcol * M + grow0]) = pk;
      } else {
#pragma unroll
        for (int r = 0; r < 4; ++r) {
          float v = acc[m][n][r];
          if (OUT_MODE == 1)
            reinterpret_cast<u16*>(Cout)[(size_t)(grow0 + r) * N + gcol] = f2bf(v);
          else
            reinterpret_cast<float*>(Cout)[(size_t)(grow0 + r) * N + gcol] = v;
        }
      }
    }
  }
}

// ---------------- flash attention v4 (causal, GQA, swapped, 8-wave) ----------------
// grid (32, 16), 512 threads = 8 waves; wave owns 16 q-rows (QBLK=128); KVBLK=64.
// qt = 31 - bx (LPT). Swapped QK^T / PV as v3. Defer-max rescale (T13, THR=8).
__global__ __launch_bounds__(512, 4) void k_attn(
    const u16* __restrict__ Q, const u16* __restrict__ K, const u16* __restrict__ VT,
    u16* __restrict__ O) {
  __shared__ __align__(16) u16 Ks[64 * 128];    // [kv][d], xor-swizzled, 16KB
  __shared__ __align__(16) u16 Vs[128 * 64];    // [d][kv], xor-swizzled, 16KB
  __shared__ __align__(16) u16 Pl[8][16 * 72];  // per-wave P[16q][64kv], PLD=72
  const int h = blockIdx.y;
  const int kvh = h >> 2;
  const int qt = 31 - blockIdx.x;
  const int tid = threadIdx.x, lane = tid & 63, wid = tid >> 6;
  const int lr = lane & 15, lhi = lane >> 4;
  const int qbase = qt * 128 + wid * 16;
  const int qglob = qbase + lr;
  const float CE = 0.12751743f;   // log2(e)/sqrt(128)
  const float THR = 62.74f;       // 8/CE (defer-max threshold, raw-score units)

  bf16x8 qf[4];
#pragma unroll
  for (int c = 0; c < 4; ++c)
    qf[c] = *reinterpret_cast<const bf16x8*>(
        &Q[(size_t)qglob * HDIM + h * HEAD_D + c * 32 + lhi * 8]);

  f32x4 o_[8] = {};
  float m_ = -3e38f, l_ = 0.f;
  char* KsB = (char*)Ks;
  char* VsB = (char*)Vs;
  u16* pw = Pl[wid];

  const int nst = 2 * qt + 2;
  for (int j = 0; j < nst; ++j) {
    const int kb = j << 6;
    __syncthreads();
    // stage K tile [64 kv][128 d]: 1024 uint4 over 512 threads
#pragma unroll
    for (int it = 0; it < 2; ++it) {
      int s = it * 512 + tid;
      int kv = s >> 4, c16 = s & 15;
      int db = kv * 256 + c16 * 16;
      db ^= ((db >> 8) & 7) << 4;
      *reinterpret_cast<uint4*>(KsB + db) = *reinterpret_cast<const uint4*>(
          &K[(size_t)(kb + kv) * KVDIM + kvh * HEAD_D + c16 * 8]);
    }
    // stage V^T tile [128 d][64 kv]: 1024 uint4
#pragma unroll
    for (int it = 0; it < 2; ++it) {
      int s = it * 512 + tid;
      int d = s >> 3, k16 = s & 7;
      int db = d * 128 + k16 * 16;
      db ^= ((db >> 7) & 7) << 4;
      *reinterpret_cast<uint4*>(VsB + db) = *reinterpret_cast<const uint4*>(
          &VT[(size_t)(kvh * HEAD_D + d) * S_LEN + kb + k16 * 8]);
    }
    __syncthreads();

    if (kb <= qbase + 15) {  // wave-uniform: this wave has unmasked rows
      // QK^T swapped: lane holds S^T[kv][q]: q = lr, kv = kb + nt*16 + lhi*4 + r
      f32x4 sf[4];
#pragma unroll
      for (int nt = 0; nt < 4; ++nt) {
        f32x4 s = {0.f, 0.f, 0.f, 0.f};
#pragma unroll
        for (int c = 0; c < 4; ++c) {
          int db = (nt * 16 + lr) * 256 + c * 64 + lhi * 16;
          db ^= ((db >> 8) & 7) << 4;
          bf16x8 kf = *reinterpret_cast<const bf16x8*>(KsB + db);
          s = __builtin_amdgcn_mfma_f32_16x16x32_bf16(kf, qf[c], s, 0, 0, 0);
        }
        sf[nt] = s;
      }
      // causal mask only near the diagonal (wave-uniform branch)
      if (kb + 63 > qbase) {
#pragma unroll
        for (int nt = 0; nt < 4; ++nt)
#pragma unroll
          for (int r = 0; r < 4; ++r)
            if (kb + nt * 16 + lhi * 4 + r > qglob) sf[nt][r] = -1e30f;
      }
      // row max: in-lane over 16 + 2 shfl
      float pm = sf[0][0];
#pragma unroll
      for (int nt = 0; nt < 4; ++nt)
#pragma unroll
        for (int r = 0; r < 4; ++r) pm = fmaxf(pm, sf[nt][r]);
      pm = fmaxf(pm, __shfl_xor(pm, 16));
      pm = fmaxf(pm, __shfl_xor(pm, 32));
      // defer-max: rescale only if some row grew beyond THR
      if (!__all(pm <= m_ + THR)) {
        float mnew = fmaxf(m_, pm);
        float fac = exp2_fast((m_ - mnew) * CE);
        m_ = mnew;
        l_ *= fac;
#pragma unroll
        for (int dt = 0; dt < 8; ++dt)
#pragma unroll
          for (int r = 0; r < 4; ++r) o_[dt][r] *= fac;
      }
      const float mc = m_ * CE;
      // p = exp2(s*CE - mc); pack bf16; in-lane sum
      float rs = 0.f;
      u32 pkw[8];
#pragma unroll
      for (int nt = 0; nt < 4; ++nt) {
        float p0 = exp2_fast(__builtin_fmaf(sf[nt][0], CE, -mc));
        float p1 = exp2_fast(__builtin_fmaf(sf[nt][1], CE, -mc));
        float p2 = exp2_fast(__builtin_fmaf(sf[nt][2], CE, -mc));
        float p3 = exp2_fast(__builtin_fmaf(sf[nt][3], CE, -mc));
        rs += (p0 + p1) + (p2 + p3);
        pkw[2 * nt] = cvt_pk_bf16(p0, p1);
        pkw[2 * nt + 1] = cvt_pk_bf16(p2, p3);
      }
      rs += __shfl_xor(rs, 16);
      rs += __shfl_xor(rs, 32);
      l_ += rs;
      // P^T -> per-wave LDS: row q=lr, cols kv; 4x ds_write_b64
#pragma unroll
      for (int nt = 0; nt < 4; ++nt) {
        uint2 w2 = make_uint2(pkw[2 * nt], pkw[2 * nt + 1]);
        *reinterpret_cast<uint2*>(&pw[lr * 72 + nt * 16 + lhi * 4]) = w2;
      }
      // PV swapped: O^T[d][q] += V^T[d][kv] * P^T[kv][q]
#pragma unroll
      for (int kk = 0; kk < 2; ++kk) {
        bf16x8 pb = *reinterpret_cast<const bf16x8*>(&pw[lr * 72 + kk * 32 + lhi * 8]);
#pragma unroll
        for (int dt = 0; dt < 8; ++dt) {
          int db = (dt * 16 + lr) * 128 + kk * 64 + lhi * 16;
          db ^= ((db >> 7) & 7) << 4;
          bf16x8 vf = *reinterpret_cast<const bf16x8*>(VsB + db);
          o_[dt] = __builtin_amdgcn_mfma_f32_16x16x32_bf16(vf, pb, o_[dt], 0, 0, 0);
        }
      }
    }
  }
  // lane holds O[q = qglob][d = dt*16 + lhi*4 + r]
  const float inv_l = 1.0f / l_;
#pragma unroll
  for (int dt = 0; dt < 8; ++dt) {
    ushort4 pk;
    pk.x = f2bf(o_[dt][0] * inv_l);
    pk.y = f2bf(o_[dt][1] * inv_l);
    pk.z = f2bf(o_[dt][2] * inv_l);
    pk.w = f2bf(o_[dt][3] * inv_l);
    *reinterpret_cast<ushort4*>(
        &O[(size_t)qglob * HDIM + h * HEAD_D + dt * 16 + lhi * 4]) = pk;
  }
}

extern "C" void kernel_launch(void* const* d_in, const int* in_sizes, int n_in,
                              void* d_out, int out_size, void* d_ws, size_t ws_size,
                              hipStream_t stream) {
  const float* hs = (const float*)d_in[0];
  const float* wq = (const float*)d_in[1];
  const float* wk = (const float*)d_in[2];
  const float* wv = (const float*)d_in[3];
  const float* wo = (const float*)d_in[4];

  char* ws = (char*)d_ws;
  size_t off = 0;
  auto alloc = [&](size_t bytes) {
    void* p = ws + off;
    off += (bytes + 255) & ~(size_t)255;
    return p;
  };
  u16* Xb = (u16*)alloc((size_t)S_LEN * HDIM * 2);
  u16* WqT = (u16*)alloc((size_t)HDIM * HDIM * 2);
  u16* WkT = (u16*)alloc((size_t)KVDIM * HDIM * 2);
  u16* WvT = (u16*)alloc((size_t)KVDIM * HDIM * 2);
  u16* WoT = (u16*)alloc((size_t)HDIM * HDIM * 2);
  u16* Qb = (u16*)alloc((size_t)S_LEN * HDIM * 2);
  u16* Kb = (u16*)alloc((size_t)S_LEN * KVDIM * 2);
  u16* VTb = (u16*)alloc((size_t)KVDIM * S_LEN * 2);  // V^T [512][4096]
  u16* Ab = (u16*)alloc((size_t)S_LEN * HDIM * 2);
  float* cosT = (float*)alloc((size_t)S_LEN * 64 * 4);
  float* sinT = (float*)alloc((size_t)S_LEN * 64 * 4);
  if (off > ws_size) return;  // workspace too small; avoid OOB

  // 1. cast hidden to bf16
  k_cast_bf16<<<dim3(S_LEN * HDIM / 8 / 256), dim3(256), 0, stream>>>(hs, Xb, S_LEN * HDIM / 8);
  // 2. transpose weights to [N][K] bf16
  k_transpose_cast<<<dim3(HDIM / 32, HDIM / 32), dim3(32, 8), 0, stream>>>(wq, WqT, HDIM, HDIM);
  k_transpose_cast<<<dim3(KVDIM / 32, HDIM / 32), dim3(32, 8), 0, stream>>>(wk, WkT, HDIM, KVDIM);
  k_transpose_cast<<<dim3(KVDIM / 32, HDIM / 32), dim3(32, 8), 0, stream>>>(wv, WvT, HDIM, KVDIM);
  k_transpose_cast<<<dim3(HDIM / 32, HDIM / 32), dim3(32, 8), 0, stream>>>(wo, WoT, HDIM, HDIM);
  // 3. rope table
  k_rope_table<<<dim3(S_LEN * 64 / 256), dim3(256), 0, stream>>>(cosT, sinT);
  // 4. QKV projections (V written transposed)
  k_gemm_bt<1><<<dim3(32, 16), dim3(256), 0, stream>>>(Xb, WqT, (void*)Qb, S_LEN, HDIM, HDIM);
  k_gemm_bt<1><<<dim3(32, 4), dim3(256), 0, stream>>>(Xb, WkT, (void*)Kb, S_LEN, KVDIM, HDIM);
  k_gemm_bt<2><<<dim3(32, 4), dim3(256), 0, stream>>>(Xb, WvT, (void*)VTb, S_LEN, KVDIM, HDIM);
  // 5. rope on Q, K
  k_rope_apply<<<dim3(S_LEN * HDIM / 8 / 256), dim3(256), 0, stream>>>(Qb, cosT, sinT, HDIM);
  k_rope_apply<<<dim3(S_LEN * KVDIM / 8 / 256), dim3(256), 0, stream>>>(Kb, cosT, sinT, KVDIM);
  // 6. attention (8-wave, QBLK=128)
  k_attn<<<dim3(32, N_HEADS), dim3(512), 0, stream>>>(Qb, Kb, VTb, Ab);
  // 7. output projection -> f32
  k_gemm_bt<0><<<dim3(32, 16), dim3(256), 0, stream>>>(Ab, WoT, d_out, S_LEN, HDIM, HDIM);
}

// Round 6
// 325.874 us; speedup vs baseline: 2.9616x; 1.2583x over previous
//
#include <hip/hip_runtime.h>

typedef unsigned short u16;
typedef unsigned int u32;
typedef __bf16 bf16x8 __attribute__((ext_vector_type(8)));
typedef float f32x4 __attribute__((ext_vector_type(4)));

#define S_LEN 4096
#define HDIM 2048
#define KVDIM 512
#define N_HEADS 16
#define HEAD_D 128

__device__ __forceinline__ u16 f2bf(float f) {
  u32 u = __float_as_uint(f);
  u32 r = (u + 0x7FFFu + ((u >> 16) & 1u)) >> 16;
  return (u16)r;
}
__device__ __forceinline__ float bf2f(u16 h) {
  return __uint_as_float(((u32)h) << 16);
}
__device__ __forceinline__ float exp2_fast(float x) {
  float r;
  asm("v_exp_f32 %0, %1" : "=v"(r) : "v"(x));
  return r;
}
__device__ __forceinline__ u32 cvt_pk_bf16(float lo, float hi) {
  u32 r;
  asm("v_cvt_pk_bf16_f32 %0, %1, %2" : "=v"(r) : "v"(lo), "v"(hi));
  return r;
}
__device__ __forceinline__ void gload16(const u16* g, u16* l) {
  __builtin_amdgcn_global_load_lds(
      (const __attribute__((address_space(1))) void*)g,
      (__attribute__((address_space(3))) void*)l, 16, 0, 0);
}

// ---------------- f32 -> bf16 cast (8 elems/thread) ----------------
__global__ void k_cast_bf16(const float* __restrict__ in, u16* __restrict__ out, int n8) {
  int i = blockIdx.x * blockDim.x + threadIdx.x;
  if (i >= n8) return;
  const float4* p = reinterpret_cast<const float4*>(in) + (size_t)i * 2;
  float4 a = p[0], b = p[1];
  u32 o0 = (u32)f2bf(a.x) | ((u32)f2bf(a.y) << 16);
  u32 o1 = (u32)f2bf(a.z) | ((u32)f2bf(a.w) << 16);
  u32 o2 = (u32)f2bf(b.x) | ((u32)f2bf(b.y) << 16);
  u32 o3 = (u32)f2bf(b.z) | ((u32)f2bf(b.w) << 16);
  reinterpret_cast<uint4*>(out)[i] = make_uint4(o0, o1, o2, o3);
}

// ---------------- W [Kd][Nd] f32 -> Wt [Nd][Kd] bf16 ----------------
__global__ void k_transpose_cast(const float* __restrict__ W, u16* __restrict__ Wt,
                                 int Kd, int Nd) {
  __shared__ float t[32][33];
  int bx = blockIdx.x, by = blockIdx.y;
  int tx = threadIdx.x, ty = threadIdx.y;
  int n = bx * 32 + tx;
  for (int j = ty; j < 32; j += 8)
    t[j][tx] = W[(size_t)(by * 32 + j) * Nd + n];
  __syncthreads();
  int k = by * 32 + tx;
  for (int j = ty; j < 32; j += 8)
    Wt[(size_t)(bx * 32 + j) * Kd + k] = f2bf(t[tx][j]);
}

// ---------------- RoPE table: cos/sin [S][64] f32 ----------------
__global__ void k_rope_table(float* __restrict__ cosT, float* __restrict__ sinT) {
  int i = blockIdx.x * blockDim.x + threadIdx.x;  // S*64
  int pos = i >> 6, f = i & 63;
  float inv = expf(-0.1439115683121279f * (float)f);  // 10000^(-f/64)
  float ang = (float)pos * inv;
  float s, c;
  sincosf(ang, &s, &c);
  cosT[i] = c;
  sinT[i] = s;
}

// ---------------- interleaved RoPE in-place on bf16 [S][width] ----------------
__global__ void k_rope_apply(u16* __restrict__ X, const float* __restrict__ cosT,
                             const float* __restrict__ sinT, int width) {
  int i = blockIdx.x * blockDim.x + threadIdx.x;  // S*width/8 threads
  size_t idx = (size_t)i * 8;
  int row = (int)(idx / width);
  int col = (int)(idx - (size_t)row * width);
  int fi = (col & 127) >> 1;  // multiple of 4
  float4 c4 = *reinterpret_cast<const float4*>(&cosT[(row << 6) + fi]);
  float4 s4 = *reinterpret_cast<const float4*>(&sinT[(row << 6) + fi]);
  uint4 v = *reinterpret_cast<const uint4*>(&X[idx]);
  float cc[4] = {c4.x, c4.y, c4.z, c4.w};
  float ss[4] = {s4.x, s4.y, s4.z, s4.w};
  u32 w_[4] = {v.x, v.y, v.z, v.w};
  u32 r_[4];
#pragma unroll
  for (int p = 0; p < 4; ++p) {
    float x1 = bf2f((u16)(w_[p] & 0xffff));
    float x2 = bf2f((u16)(w_[p] >> 16));
    float r1 = x1 * cc[p] - x2 * ss[p];
    float r2 = x1 * ss[p] + x2 * cc[p];
    r_[p] = (u32)f2bf(r1) | ((u32)f2bf(r2) << 16);
  }
  *reinterpret_cast<uint4*>(&X[idx]) = make_uint4(r_[0], r_[1], r_[2], r_[3]);
}

// ---------------- GEMM: C[M][N] = A[M][K](bf16) * Bt[N][K](bf16)^T ----------------
// m97 structure: 128x128 tile, BK=32, linear LDS [128][32], global_load_lds w=16.
// OUT_MODE: 0 = f32 C[M][N]; 1 = bf16 C[M][N]; 2 = bf16 C^T[N][M] (packed ushort4)
template <int OUT_MODE>
__global__ __launch_bounds__(256) void k_gemm_bt(
    const u16* __restrict__ A, const u16* __restrict__ Bt, void* __restrict__ Cout,
    int M, int N, int Kd) {
  __shared__ __align__(16) u16 As[128 * 32];
  __shared__ __align__(16) u16 Bs[128 * 32];
  const int bm = blockIdx.x * 128;
  const int bn = blockIdx.y * 128;
  const int tid = threadIdx.x;
  const int lane = tid & 63;
  const int wid = tid >> 6;
  const int wr = (wid >> 1) * 64, wc = (wid & 1) * 64;
  const int lr = lane & 15, lhi = lane >> 4;
  const int srow = lane >> 2;          // 0..15 within 16-row chunk
  const int skc = (lane & 3) * 8;      // 0,8,16,24
  f32x4 acc[4][4] = {};
  for (int k0 = 0; k0 < Kd; k0 += 32) {
#pragma unroll
    for (int it = 0; it < 2; ++it) {
      int rowbase = (it * 4 + wid) * 16;
      gload16(&A[(size_t)(bm + rowbase + srow) * Kd + k0 + skc], &As[rowbase * 32]);
      gload16(&Bt[(size_t)(bn + rowbase + srow) * Kd + k0 + skc], &Bs[rowbase * 32]);
    }
    __syncthreads();
    bf16x8 af[4], bfr[4];
#pragma unroll
    for (int m = 0; m < 4; ++m)
      af[m] = *reinterpret_cast<const bf16x8*>(&As[(wr + m * 16 + lr) * 32 + lhi * 8]);
#pragma unroll
    for (int n = 0; n < 4; ++n)
      bfr[n] = *reinterpret_cast<const bf16x8*>(&Bs[(wc + n * 16 + lr) * 32 + lhi * 8]);
#pragma unroll
    for (int m = 0; m < 4; ++m)
#pragma unroll
      for (int n = 0; n < 4; ++n)
        acc[m][n] = __builtin_amdgcn_mfma_f32_16x16x32_bf16(af[m], bfr[n], acc[m][n], 0, 0, 0);
    __syncthreads();
  }
#pragma unroll
  for (int m = 0; m < 4; ++m) {
    int grow0 = bm + wr + m * 16 + lhi * 4;
#pragma unroll
    for (int n = 0; n < 4; ++n) {
      int gcol = bn + wc + n * 16 + lr;
      if (OUT_MODE == 2) {
        ushort4 pk;
        pk.x = f2bf(acc[m][n][0]);
        pk.y = f2bf(acc[m][n][1]);
        pk.z = f2bf(acc[m][n][2]);
        pk.w = f2bf(acc[m][n][3]);
        *reinterpret_cast<ushort4*>(
            &reinterpret_cast<u16*>(Cout)[(size_t)gcol * M + grow0]) = pk;
      } else {
#pragma unroll
        for (int r = 0; r < 4; ++r) {
          float v = acc[m][n][r];
          if (OUT_MODE == 1)
            reinterpret_cast<u16*>(Cout)[(size_t)(grow0 + r) * N + gcol] = f2bf(v);
          else
            reinterpret_cast<float*>(Cout)[(size_t)(grow0 + r) * N + gcol] = v;
        }
      }
    }
  }
}

// ---------------- merged K+V projection (grid 32 x 8) ----------------
// by<4: K = X*WkT^T -> Kb bf16 [4096][512]; by>=4: V -> VTb bf16 C^T [512][4096]
__global__ __launch_bounds__(256) void k_gemm_kv(
    const u16* __restrict__ A, const u16* __restrict__ WkT, const u16* __restrict__ WvT,
    u16* __restrict__ Kb, u16* __restrict__ VTb) {
  const int Kd = HDIM, M = S_LEN, N = KVDIM;
  __shared__ __align__(16) u16 As[128 * 32];
  __shared__ __align__(16) u16 Bs[128 * 32];
  const int bm = blockIdx.x * 128;
  const bool isV = blockIdx.y >= 4;
  const int bn = (blockIdx.y & 3) * 128;
  const u16* Bt = isV ? WvT : WkT;
  const int tid = threadIdx.x;
  const int lane = tid & 63;
  const int wid = tid >> 6;
  const int wr = (wid >> 1) * 64, wc = (wid & 1) * 64;
  const int lr = lane & 15, lhi = lane >> 4;
  const int srow = lane >> 2;
  const int skc = (lane & 3) * 8;
  f32x4 acc[4][4] = {};
  for (int k0 = 0; k0 < Kd; k0 += 32) {
#pragma unroll
    for (int it = 0; it < 2; ++it) {
      int rowbase = (it * 4 + wid) * 16;
      gload16(&A[(size_t)(bm + rowbase + srow) * Kd + k0 + skc], &As[rowbase * 32]);
      gload16(&Bt[(size_t)(bn + rowbase + srow) * Kd + k0 + skc], &Bs[rowbase * 32]);
    }
    __syncthreads();
    bf16x8 af[4], bfr[4];
#pragma unroll
    for (int m = 0; m < 4; ++m)
      af[m] = *reinterpret_cast<const bf16x8*>(&As[(wr + m * 16 + lr) * 32 + lhi * 8]);
#pragma unroll
    for (int n = 0; n < 4; ++n)
      bfr[n] = *reinterpret_cast<const bf16x8*>(&Bs[(wc + n * 16 + lr) * 32 + lhi * 8]);
#pragma unroll
    for (int m = 0; m < 4; ++m)
#pragma unroll
      for (int n = 0; n < 4; ++n)
        acc[m][n] = __builtin_amdgcn_mfma_f32_16x16x32_bf16(af[m], bfr[n], acc[m][n], 0, 0, 0);
    __syncthreads();
  }
#pragma unroll
  for (int m = 0; m < 4; ++m) {
    int grow0 = bm + wr + m * 16 + lhi * 4;
#pragma unroll
    for (int n = 0; n < 4; ++n) {
      int gcol = bn + wc + n * 16 + lr;
      if (isV) {
        ushort4 pk;
        pk.x = f2bf(acc[m][n][0]);
        pk.y = f2bf(acc[m][n][1]);
        pk.z = f2bf(acc[m][n][2]);
        pk.w = f2bf(acc[m][n][3]);
        *reinterpret_cast<ushort4*>(&VTb[(size_t)gcol * M + grow0]) = pk;
      } else {
#pragma unroll
        for (int r = 0; r < 4; ++r)
          Kb[(size_t)(grow0 + r) * N + gcol] = f2bf(acc[m][n][r]);
      }
    }
  }
}

// ---------------- flash attention v5 (causal, GQA, swapped, 8-wave) ----------------
// 1D grid 512; complementary pairing: blocks i and i+256 have qt summing to 31,
// so any CU receiving both gets a constant 66-tile workload.
__global__ __launch_bounds__(512, 4) void k_attn(
    const u16* __restrict__ Q, const u16* __restrict__ K, const u16* __restrict__ VT,
    u16* __restrict__ O) {
  __shared__ __align__(16) u16 Ks[64 * 128];    // [kv][d], xor-swizzled, 16KB
  __shared__ __align__(16) u16 Vs[128 * 64];    // [d][kv], xor-swizzled, 16KB
  __shared__ __align__(16) u16 Pl[8][16 * 72];  // per-wave P[16q][64kv], PLD=72
  int i = blockIdx.x;
  int qt, h;
  if (i < 256) { qt = 16 + (i & 15); h = i >> 4; }
  else { int jj = i - 256; qt = 15 - (jj & 15); h = jj >> 4; }
  const int kvh = h >> 2;
  const int tid = threadIdx.x, lane = tid & 63, wid = tid >> 6;
  const int lr = lane & 15, lhi = lane >> 4;
  const int qbase = qt * 128 + wid * 16;
  const int qglob = qbase + lr;
  const float CE = 0.12751743f;   // log2(e)/sqrt(128)
  const float THR = 62.74f;       // 8/CE (defer-max threshold, raw-score units)

  bf16x8 qf[4];
#pragma unroll
  for (int c = 0; c < 4; ++c)
    qf[c] = *reinterpret_cast<const bf16x8*>(
        &Q[(size_t)qglob * HDIM + h * HEAD_D + c * 32 + lhi * 8]);

  f32x4 o_[8] = {};
  float m_ = -3e38f, l_ = 0.f;
  char* KsB = (char*)Ks;
  char* VsB = (char*)Vs;
  u16* pw = Pl[wid];

  const int nst = 2 * qt + 2;
  for (int j = 0; j < nst; ++j) {
    const int kb = j << 6;
    __syncthreads();
    // stage K tile [64 kv][128 d]: 1024 uint4 over 512 threads
#pragma unroll
    for (int it = 0; it < 2; ++it) {
      int s = it * 512 + tid;
      int kv = s >> 4, c16 = s & 15;
      int db = kv * 256 + c16 * 16;
      db ^= ((db >> 8) & 7) << 4;
      *reinterpret_cast<uint4*>(KsB + db) = *reinterpret_cast<const uint4*>(
          &K[(size_t)(kb + kv) * KVDIM + kvh * HEAD_D + c16 * 8]);
    }
    // stage V^T tile [128 d][64 kv]: 1024 uint4
#pragma unroll
    for (int it = 0; it < 2; ++it) {
      int s = it * 512 + tid;
      int d = s >> 3, k16 = s & 7;
      int db = d * 128 + k16 * 16;
      db ^= ((db >> 7) & 7) << 4;
      *reinterpret_cast<uint4*>(VsB + db) = *reinterpret_cast<const uint4*>(
          &VT[(size_t)(kvh * HEAD_D + d) * S_LEN + kb + k16 * 8]);
    }
    __syncthreads();

    if (kb <= qbase + 15) {  // wave-uniform: this wave has unmasked rows
      // QK^T swapped: lane holds S^T[kv][q]: q = lr, kv = kb + nt*16 + lhi*4 + r
      f32x4 sf[4];
#pragma unroll
      for (int nt = 0; nt < 4; ++nt) {
        f32x4 s = {0.f, 0.f, 0.f, 0.f};
#pragma unroll
        for (int c = 0; c < 4; ++c) {
          int db = (nt * 16 + lr) * 256 + c * 64 + lhi * 16;
          db ^= ((db >> 8) & 7) << 4;
          bf16x8 kf = *reinterpret_cast<const bf16x8*>(KsB + db);
          s = __builtin_amdgcn_mfma_f32_16x16x32_bf16(kf, qf[c], s, 0, 0, 0);
        }
        sf[nt] = s;
      }
      // causal mask only near the diagonal (wave-uniform branch)
      if (kb + 63 > qbase) {
#pragma unroll
        for (int nt = 0; nt < 4; ++nt)
#pragma unroll
          for (int r = 0; r < 4; ++r)
            if (kb + nt * 16 + lhi * 4 + r > qglob) sf[nt][r] = -1e30f;
      }
      // row max: in-lane over 16 + 2 shfl
      float pm = sf[0][0];
#pragma unroll
      for (int nt = 0; nt < 4; ++nt)
#pragma unroll
        for (int r = 0; r < 4; ++r) pm = fmaxf(pm, sf[nt][r]);
      pm = fmaxf(pm, __shfl_xor(pm, 16));
      pm = fmaxf(pm, __shfl_xor(pm, 32));
      // defer-max: rescale only if some row grew beyond THR
      if (!__all(pm <= m_ + THR)) {
        float mnew = fmaxf(m_, pm);
        float fac = exp2_fast((m_ - mnew) * CE);
        m_ = mnew;
        l_ *= fac;
#pragma unroll
        for (int dt = 0; dt < 8; ++dt)
#pragma unroll
          for (int r = 0; r < 4; ++r) o_[dt][r] *= fac;
      }
      const float mc = m_ * CE;
      // p = exp2(s*CE - mc); pack bf16; in-lane sum
      float rs = 0.f;
      u32 pkw[8];
#pragma unroll
      for (int nt = 0; nt < 4; ++nt) {
        float p0 = exp2_fast(__builtin_fmaf(sf[nt][0], CE, -mc));
        float p1 = exp2_fast(__builtin_fmaf(sf[nt][1], CE, -mc));
        float p2 = exp2_fast(__builtin_fmaf(sf[nt][2], CE, -mc));
        float p3 = exp2_fast(__builtin_fmaf(sf[nt][3], CE, -mc));
        rs += (p0 + p1) + (p2 + p3);
        pkw[2 * nt] = cvt_pk_bf16(p0, p1);
        pkw[2 * nt + 1] = cvt_pk_bf16(p2, p3);
      }
      rs += __shfl_xor(rs, 16);
      rs += __shfl_xor(rs, 32);
      l_ += rs;
      // P^T -> per-wave LDS: row q=lr, cols kv; 4x ds_write_b64
#pragma unroll
      for (int nt = 0; nt < 4; ++nt) {
        uint2 w2 = make_uint2(pkw[2 * nt], pkw[2 * nt + 1]);
        *reinterpret_cast<uint2*>(&pw[lr * 72 + nt * 16 + lhi * 4]) = w2;
      }
      // PV swapped: O^T[d][q] += V^T[d][kv] * P^T[kv][q]
#pragma unroll
      for (int kk = 0; kk < 2; ++kk) {
        bf16x8 pb = *reinterpret_cast<const bf16x8*>(&pw[lr * 72 + kk * 32 + lhi * 8]);
#pragma unroll
        for (int dt = 0; dt < 8; ++dt) {
          int db = (dt * 16 + lr) * 128 + kk * 64 + lhi * 16;
          db ^= ((db >> 7) & 7) << 4;
          bf16x8 vf = *reinterpret_cast<const bf16x8*>(VsB + db);
          o_[dt] = __builtin_amdgcn_mfma_f32_16x16x32_bf16(vf, pb, o_[dt], 0, 0, 0);
        }
      }
    }
  }
  // lane holds O[q = qglob][d = dt*16 + lhi*4 + r]
  const float inv_l = 1.0f / l_;
#pragma unroll
  for (int dt = 0; dt < 8; ++dt) {
    ushort4 pk;
    pk.x = f2bf(o_[dt][0] * inv_l);
    pk.y = f2bf(o_[dt][1] * inv_l);
    pk.z = f2bf(o_[dt][2] * inv_l);
    pk.w = f2bf(o_[dt][3] * inv_l);
    *reinterpret_cast<ushort4*>(
        &O[(size_t)qglob * HDIM + h * HEAD_D + dt * 16 + lhi * 4]) = pk;
  }
}

extern "C" void kernel_launch(void* const* d_in, const int* in_sizes, int n_in,
                              void* d_out, int out_size, void* d_ws, size_t ws_size,
                              hipStream_t stream) {
  const float* hs = (const float*)d_in[0];
  const float* wq = (const float*)d_in[1];
  const float* wk = (const float*)d_in[2];
  const float* wv = (const float*)d_in[3];
  const float* wo = (const float*)d_in[4];

  char* ws = (char*)d_ws;
  size_t off = 0;
  auto alloc = [&](size_t bytes) {
    void* p = ws + off;
    off += (bytes + 255) & ~(size_t)255;
    return p;
  };
  u16* Xb = (u16*)alloc((size_t)S_LEN * HDIM * 2);
  u16* WqT = (u16*)alloc((size_t)HDIM * HDIM * 2);
  u16* WkT = (u16*)alloc((size_t)KVDIM * HDIM * 2);
  u16* WvT = (u16*)alloc((size_t)KVDIM * HDIM * 2);
  u16* WoT = (u16*)alloc((size_t)HDIM * HDIM * 2);
  u16* Qb = (u16*)alloc((size_t)S_LEN * HDIM * 2);
  u16* Kb = (u16*)alloc((size_t)S_LEN * KVDIM * 2);
  u16* VTb = (u16*)alloc((size_t)KVDIM * S_LEN * 2);  // V^T [512][4096]
  u16* Ab = (u16*)alloc((size_t)S_LEN * HDIM * 2);
  float* cosT = (float*)alloc((size_t)S_LEN * 64 * 4);
  float* sinT = (float*)alloc((size_t)S_LEN * 64 * 4);
  if (off > ws_size) return;  // workspace too small; avoid OOB

  // 1. cast hidden to bf16
  k_cast_bf16<<<dim3(S_LEN * HDIM / 8 / 256), dim3(256), 0, stream>>>(hs, Xb, S_LEN * HDIM / 8);
  // 2. transpose weights to [N][K] bf16
  k_transpose_cast<<<dim3(HDIM / 32, HDIM / 32), dim3(32, 8), 0, stream>>>(wq, WqT, HDIM, HDIM);
  k_transpose_cast<<<dim3(KVDIM / 32, HDIM / 32), dim3(32, 8), 0, stream>>>(wk, WkT, HDIM, KVDIM);
  k_transpose_cast<<<dim3(KVDIM / 32, HDIM / 32), dim3(32, 8), 0, stream>>>(wv, WvT, HDIM, KVDIM);
  k_transpose_cast<<<dim3(HDIM / 32, HDIM / 32), dim3(32, 8), 0, stream>>>(wo, WoT, HDIM, HDIM);
  // 3. rope table
  k_rope_table<<<dim3(S_LEN * 64 / 256), dim3(256), 0, stream>>>(cosT, sinT);
  // 4. QKV projections (K+V merged; V written transposed)
  k_gemm_bt<1><<<dim3(32, 16), dim3(256), 0, stream>>>(Xb, WqT, (void*)Qb, S_LEN, HDIM, HDIM);
  k_gemm_kv<<<dim3(32, 8), dim3(256), 0, stream>>>(Xb, WkT, WvT, Kb, VTb);
  // 5. rope on Q, K
  k_rope_apply<<<dim3(S_LEN * HDIM / 8 / 256), dim3(256), 0, stream>>>(Qb, cosT, sinT, HDIM);
  k_rope_apply<<<dim3(S_LEN * KVDIM / 8 / 256), dim3(256), 0, stream>>>(Kb, cosT, sinT, KVDIM);
  // 6. attention (8-wave, QBLK=128, complementary pairing)
  k_attn<<<dim3(512), dim3(512), 0, stream>>>(Qb, Kb, VTb, Ab);
  // 7. output projection -> f32
  k_gemm_bt<0><<<dim3(32, 16), dim3(256), 0, stream>>>(Ab, WoT, d_out, S_LEN, HDIM, HDIM);
}

// Round 7
// 294.586 us; speedup vs baseline: 3.2761x; 1.1062x over previous
//
#include <hip/hip_runtime.h>

typedef unsigned short u16;
typedef unsigned int u32;
typedef __bf16 bf16x8 __attribute__((ext_vector_type(8)));
typedef float f32x4 __attribute__((ext_vector_type(4)));
typedef float f32x16 __attribute__((ext_vector_type(16)));
typedef int v2i __attribute__((ext_vector_type(2)));

#define S_LEN 4096
#define HDIM 2048
#define KVDIM 512
#define N_HEADS 16
#define HEAD_D 128

__device__ __forceinline__ u16 f2bf(float f) {
  u32 u = __float_as_uint(f);
  u32 r = (u + 0x7FFFu + ((u >> 16) & 1u)) >> 16;
  return (u16)r;
}
__device__ __forceinline__ float bf2f(u16 h) {
  return __uint_as_float(((u32)h) << 16);
}
__device__ __forceinline__ float exp2_fast(float x) {
  float r;
  asm("v_exp_f32 %0, %1" : "=v"(r) : "v"(x));
  return r;
}
__device__ __forceinline__ u32 cvt_pk_bf16(float lo, float hi) {
  u32 r;
  asm("v_cvt_pk_bf16_f32 %0, %1, %2" : "=v"(r) : "v"(lo), "v"(hi));
  return r;
}
__device__ __forceinline__ void gload16(const u16* g, u16* l) {
  __builtin_amdgcn_global_load_lds(
      (const __attribute__((address_space(1))) void*)g,
      (__attribute__((address_space(3))) void*)l, 16, 0, 0);
}

// ---------------- f32 -> bf16 cast (8 elems/thread) ----------------
__global__ void k_cast_bf16(const float* __restrict__ in, u16* __restrict__ out, int n8) {
  int i = blockIdx.x * blockDim.x + threadIdx.x;
  if (i >= n8) return;
  const float4* p = reinterpret_cast<const float4*>(in) + (size_t)i * 2;
  float4 a = p[0], b = p[1];
  u32 o0 = (u32)f2bf(a.x) | ((u32)f2bf(a.y) << 16);
  u32 o1 = (u32)f2bf(a.z) | ((u32)f2bf(a.w) << 16);
  u32 o2 = (u32)f2bf(b.x) | ((u32)f2bf(b.y) << 16);
  u32 o3 = (u32)f2bf(b.z) | ((u32)f2bf(b.w) << 16);
  reinterpret_cast<uint4*>(out)[i] = make_uint4(o0, o1, o2, o3);
}

// ---------------- W [Kd][Nd] f32 -> Wt [Nd][Kd] bf16 ----------------
__global__ void k_transpose_cast(const float* __restrict__ W, u16* __restrict__ Wt,
                                 int Kd, int Nd) {
  __shared__ float t[32][33];
  int bx = blockIdx.x, by = blockIdx.y;
  int tx = threadIdx.x, ty = threadIdx.y;
  int n = bx * 32 + tx;
  for (int j = ty; j < 32; j += 8)
    t[j][tx] = W[(size_t)(by * 32 + j) * Nd + n];
  __syncthreads();
  int k = by * 32 + tx;
  for (int j = ty; j < 32; j += 8)
    Wt[(size_t)(bx * 32 + j) * Kd + k] = f2bf(t[tx][j]);
}

// ---------------- RoPE table: cos/sin [S][64] f32 ----------------
__global__ void k_rope_table(float* __restrict__ cosT, float* __restrict__ sinT) {
  int i = blockIdx.x * blockDim.x + threadIdx.x;  // S*64
  int pos = i >> 6, f = i & 63;
  float inv = expf(-0.1439115683121279f * (float)f);  // 10000^(-f/64)
  float ang = (float)pos * inv;
  float s, c;
  sincosf(ang, &s, &c);
  cosT[i] = c;
  sinT[i] = s;
}

// ---------------- interleaved RoPE in-place on bf16 [S][width] ----------------
__global__ void k_rope_apply(u16* __restrict__ X, const float* __restrict__ cosT,
                             const float* __restrict__ sinT, int width) {
  int i = blockIdx.x * blockDim.x + threadIdx.x;  // S*width/8 threads
  size_t idx = (size_t)i * 8;
  int row = (int)(idx / width);
  int col = (int)(idx - (size_t)row * width);
  int fi = (col & 127) >> 1;  // multiple of 4
  float4 c4 = *reinterpret_cast<const float4*>(&cosT[(row << 6) + fi]);
  float4 s4 = *reinterpret_cast<const float4*>(&sinT[(row << 6) + fi]);
  uint4 v = *reinterpret_cast<const uint4*>(&X[idx]);
  float cc[4] = {c4.x, c4.y, c4.z, c4.w};
  float ss[4] = {s4.x, s4.y, s4.z, s4.w};
  u32 w_[4] = {v.x, v.y, v.z, v.w};
  u32 r_[4];
#pragma unroll
  for (int p = 0; p < 4; ++p) {
    float x1 = bf2f((u16)(w_[p] & 0xffff));
    float x2 = bf2f((u16)(w_[p] >> 16));
    float r1 = x1 * cc[p] - x2 * ss[p];
    float r2 = x1 * ss[p] + x2 * cc[p];
    r_[p] = (u32)f2bf(r1) | ((u32)f2bf(r2) << 16);
  }
  *reinterpret_cast<uint4*>(&X[idx]) = make_uint4(r_[0], r_[1], r_[2], r_[3]);
}

// ---------------- merged QKV projection (grid 32 x 24) ----------------
// by<16: Q -> Qb bf16 [4096][2048]; by 16-19: K -> Kb bf16 [4096][512];
// by 20-23: V -> VTb bf16 C^T [512][4096]. m97 structure.
__global__ __launch_bounds__(256) void k_gemm_qkv(
    const u16* __restrict__ A, const u16* __restrict__ WqT, const u16* __restrict__ WkT,
    const u16* __restrict__ WvT, u16* __restrict__ Qb, u16* __restrict__ Kb,
    u16* __restrict__ VTb) {
  const int Kd = HDIM, M = S_LEN;
  __shared__ __align__(16) u16 As[128 * 32];
  __shared__ __align__(16) u16 Bs[128 * 32];
  const int by = blockIdx.y;
  const u16* Bt;
  int bn, N, mode;  // mode 0: Qb, 1: Kb, 2: VTb^T
  if (by < 16) { Bt = WqT; bn = by * 128; N = HDIM; mode = 0; }
  else if (by < 20) { Bt = WkT; bn = (by - 16) * 128; N = KVDIM; mode = 1; }
  else { Bt = WvT; bn = (by - 20) * 128; N = KVDIM; mode = 2; }
  const int bm = blockIdx.x * 128;
  const int tid = threadIdx.x;
  const int lane = tid & 63;
  const int wid = tid >> 6;
  const int wr = (wid >> 1) * 64, wc = (wid & 1) * 64;
  const int lr = lane & 15, lhi = lane >> 4;
  const int srow = lane >> 2;
  const int skc = (lane & 3) * 8;
  f32x4 acc[4][4] = {};
  for (int k0 = 0; k0 < Kd; k0 += 32) {
#pragma unroll
    for (int it = 0; it < 2; ++it) {
      int rowbase = (it * 4 + wid) * 16;
      gload16(&A[(size_t)(bm + rowbase + srow) * Kd + k0 + skc], &As[rowbase * 32]);
      gload16(&Bt[(size_t)(bn + rowbase + srow) * Kd + k0 + skc], &Bs[rowbase * 32]);
    }
    __syncthreads();
    bf16x8 af[4], bfr[4];
#pragma unroll
    for (int m = 0; m < 4; ++m)
      af[m] = *reinterpret_cast<const bf16x8*>(&As[(wr + m * 16 + lr) * 32 + lhi * 8]);
#pragma unroll
    for (int n = 0; n < 4; ++n)
      bfr[n] = *reinterpret_cast<const bf16x8*>(&Bs[(wc + n * 16 + lr) * 32 + lhi * 8]);
#pragma unroll
    for (int m = 0; m < 4; ++m)
#pragma unroll
      for (int n = 0; n < 4; ++n)
        acc[m][n] = __builtin_amdgcn_mfma_f32_16x16x32_bf16(af[m], bfr[n], acc[m][n], 0, 0, 0);
    __syncthreads();
  }
#pragma unroll
  for (int m = 0; m < 4; ++m) {
    int grow0 = bm + wr + m * 16 + lhi * 4;
#pragma unroll
    for (int n = 0; n < 4; ++n) {
      int gcol = bn + wc + n * 16 + lr;
      if (mode == 2) {
        ushort4 pk;
        pk.x = f2bf(acc[m][n][0]);
        pk.y = f2bf(acc[m][n][1]);
        pk.z = f2bf(acc[m][n][2]);
        pk.w = f2bf(acc[m][n][3]);
        *reinterpret_cast<ushort4*>(&VTb[(size_t)gcol * M + grow0]) = pk;
      } else {
        u16* outp = (mode == 0) ? Qb : Kb;
#pragma unroll
        for (int r = 0; r < 4; ++r)
          outp[(size_t)(grow0 + r) * N + gcol] = f2bf(acc[m][n][r]);
      }
    }
  }
}

// ---------------- out-proj GEMM: C[M][N] f32 = A[M][K] * Bt[N][K]^T ----------------
__global__ __launch_bounds__(256) void k_gemm_bt(
    const u16* __restrict__ A, const u16* __restrict__ Bt, float* __restrict__ Cout,
    int M, int N, int Kd) {
  __shared__ __align__(16) u16 As[128 * 32];
  __shared__ __align__(16) u16 Bs[128 * 32];
  const int bm = blockIdx.x * 128;
  const int bn = blockIdx.y * 128;
  const int tid = threadIdx.x;
  const int lane = tid & 63;
  const int wid = tid >> 6;
  const int wr = (wid >> 1) * 64, wc = (wid & 1) * 64;
  const int lr = lane & 15, lhi = lane >> 4;
  const int srow = lane >> 2;
  const int skc = (lane & 3) * 8;
  f32x4 acc[4][4] = {};
  for (int k0 = 0; k0 < Kd; k0 += 32) {
#pragma unroll
    for (int it = 0; it < 2; ++it) {
      int rowbase = (it * 4 + wid) * 16;
      gload16(&A[(size_t)(bm + rowbase + srow) * Kd + k0 + skc], &As[rowbase * 32]);
      gload16(&Bt[(size_t)(bn + rowbase + srow) * Kd + k0 + skc], &Bs[rowbase * 32]);
    }
    __syncthreads();
    bf16x8 af[4], bfr[4];
#pragma unroll
    for (int m = 0; m < 4; ++m)
      af[m] = *reinterpret_cast<const bf16x8*>(&As[(wr + m * 16 + lr) * 32 + lhi * 8]);
#pragma unroll
    for (int n = 0; n < 4; ++n)
      bfr[n] = *reinterpret_cast<const bf16x8*>(&Bs[(wc + n * 16 + lr) * 32 + lhi * 8]);
#pragma unroll
    for (int m = 0; m < 4; ++m)
#pragma unroll
      for (int n = 0; n < 4; ++n)
        acc[m][n] = __builtin_amdgcn_mfma_f32_16x16x32_bf16(af[m], bfr[n], acc[m][n], 0, 0, 0);
    __syncthreads();
  }
#pragma unroll
  for (int m = 0; m < 4; ++m) {
    int grow0 = bm + wr + m * 16 + lhi * 4;
#pragma unroll
    for (int n = 0; n < 4; ++n) {
      int gcol = bn + wc + n * 16 + lr;
#pragma unroll
      for (int r = 0; r < 4; ++r)
        Cout[(size_t)(grow0 + r) * N + gcol] = acc[m][n][r];
    }
  }
}

// ---------------- flash attention v6: 4 waves x 32q, 32x32x16 MFMA ----------------
// In-register P via cvt_pk_bf16 + permlane32_swap (no P LDS). KVBLK=64.
// Complementary pairing: blocks i, i+256 have qt summing to 31.
// S^T C-layout (verified m74/m101): col q = lane&31, row kv = (reg&3)+8*(reg>>2)+4*(lane>>5)
__global__ __launch_bounds__(256, 2) void k_attn(
    const u16* __restrict__ Q, const u16* __restrict__ K, const u16* __restrict__ VT,
    u16* __restrict__ O) {
  __shared__ __align__(16) u16 Ks[64 * 128];   // [kv][d], xor-swizzled, 16KB
  __shared__ __align__(16) u16 Vs[128 * 64];   // [d][kv], xor-swizzled, 16KB
  int i = blockIdx.x;
  int qt, h;
  if (i < 256) { qt = 16 + (i & 15); h = i >> 4; }
  else { int jj = i - 256; qt = 15 - (jj & 15); h = jj >> 4; }
  const int kvh = h >> 2;
  const int tid = threadIdx.x, lane = tid & 63, wid = tid >> 6;
  const int l31 = lane & 31, hi = lane >> 5;
  const int qw = qt * 128 + wid * 32;
  const int qglob = qw + l31;
  const float CE = 0.12751743f;   // log2(e)/sqrt(128)
  const float THR = 62.74f;       // 8/CE

  // Q as B-operand: col q = l31, k(d) = ks*16 + hi*8 + j
  const u16* qptr = &Q[(size_t)qglob * HDIM + h * HEAD_D];
  bf16x8 qf[8];
#pragma unroll
  for (int ks = 0; ks < 8; ++ks)
    qf[ks] = *reinterpret_cast<const bf16x8*>(&qptr[ks * 16 + hi * 8]);

  f32x16 o_[4] = {};
  float m_ = -3e38f, l_ = 0.f;
  char* KsB = (char*)Ks;
  char* VsB = (char*)Vs;

  const int nst = 2 * qt + 2;
  for (int j = 0; j < nst; ++j) {
    const int kb = j << 6;
    __syncthreads();
    // stage K tile [64 kv][128 d]: 1024 uint4 over 256 threads
#pragma unroll
    for (int it = 0; it < 4; ++it) {
      int s = it * 256 + tid;
      int kv = s >> 4, c16 = s & 15;
      int db = kv * 256 + c16 * 16;
      db ^= ((db >> 8) & 7) << 4;
      *reinterpret_cast<uint4*>(KsB + db) = *reinterpret_cast<const uint4*>(
          &K[(size_t)(kb + kv) * KVDIM + kvh * HEAD_D + c16 * 8]);
    }
    // stage V^T tile [128 d][64 kv]: 1024 uint4
#pragma unroll
    for (int it = 0; it < 4; ++it) {
      int s = it * 256 + tid;
      int d = s >> 3, k16 = s & 7;
      int db = d * 128 + k16 * 16;
      db ^= ((db >> 7) & 7) << 4;
      *reinterpret_cast<uint4*>(VsB + db) = *reinterpret_cast<const uint4*>(
          &VT[(size_t)(kvh * HEAD_D + d) * S_LEN + kb + k16 * 8]);
    }
    __syncthreads();

    if (kb <= qw + 31) {  // wave-uniform participation
      // QK^T swapped: S^T[64kv][32q], two 32x32 tiles (kvt 0,1), interleaved chains
      f32x16 s0 = {}, s1 = {};
#pragma unroll
      for (int ks = 0; ks < 8; ++ks) {
        int db0 = l31 * 256 + ks * 32 + hi * 16;
        db0 ^= ((db0 >> 8) & 7) << 4;
        int db1 = (32 + l31) * 256 + ks * 32 + hi * 16;
        db1 ^= ((db1 >> 8) & 7) << 4;
        bf16x8 k0 = *reinterpret_cast<const bf16x8*>(KsB + db0);
        bf16x8 k1 = *reinterpret_cast<const bf16x8*>(KsB + db1);
        s0 = __builtin_amdgcn_mfma_f32_32x32x16_bf16(k0, qf[ks], s0, 0, 0, 0);
        s1 = __builtin_amdgcn_mfma_f32_32x32x16_bf16(k1, qf[ks], s1, 0, 0, 0);
      }
      // causal mask near diagonal (wave-uniform branch)
      if (kb + 63 > qw) {
#pragma unroll
        for (int r = 0; r < 16; ++r) {
          int kvr = kb + (r & 3) + 8 * (r >> 2) + 4 * hi;
          if (kvr > qglob) s0[r] = -1e30f;
          if (kvr + 32 > qglob) s1[r] = -1e30f;
        }
      }
      // row max: in-lane over 32 + xor32 (partner lane holds other half of row)
      float pm = fmaxf(s0[0], s1[0]);
#pragma unroll
      for (int r = 1; r < 16; ++r) pm = fmaxf(pm, fmaxf(s0[r], s1[r]));
      pm = fmaxf(pm, __shfl_xor(pm, 32));
      // defer-max rescale
      if (!__all(pm <= m_ + THR)) {
        float mnew = fmaxf(m_, pm);
        float fac = exp2_fast((m_ - mnew) * CE);
        m_ = mnew;
        l_ *= fac;
#pragma unroll
        for (int dt = 0; dt < 4; ++dt)
#pragma unroll
          for (int r = 0; r < 16; ++r) o_[dt][r] *= fac;
      }
      const float mc = m_ * CE;
      float rs = 0.f;
#pragma unroll
      for (int r = 0; r < 16; ++r) {
        s0[r] = exp2_fast(__builtin_fmaf(s0[r], CE, -mc));
        s1[r] = exp2_fast(__builtin_fmaf(s1[r], CE, -mc));
        rs += s0[r] + s1[r];
      }
      rs += __shfl_xor(rs, 32);
      l_ += rs;
      // per kvt: pack P to bf16, redistribute halves via permlane32_swap, PV
#pragma unroll
      for (int kvt = 0; kvt < 2; ++kvt) {
        u32 xw[8], yw[8];
#pragma unroll
        for (int g = 0; g < 8; ++g) {
          float plo = kvt ? s1[2 * g] : s0[2 * g];
          float phi = kvt ? s1[2 * g + 1] : s0[2 * g + 1];
          u32 pw = cvt_pk_bf16(plo, phi);
          v2i sw = __builtin_amdgcn_permlane32_swap((int)pw, (int)pw, false, false);
          xw[g] = (u32)sw[0];  // lo-row broadcast: kv (0,1)+8g' group
          yw[g] = (u32)sw[1];  // hi-row broadcast: kv (4,5)+8g' group
        }
#pragma unroll
        for (int ksl = 0; ksl < 2; ++ksl) {
          int b = ksl * 4;
          u32 f0 = hi ? xw[b + 2] : xw[b + 0];
          u32 f1 = hi ? xw[b + 3] : xw[b + 1];
          u32 f2 = hi ? yw[b + 2] : yw[b + 0];
          u32 f3 = hi ? yw[b + 3] : yw[b + 1];
          uint4 fr = make_uint4(f0, f1, f2, f3);
          bf16x8 pf = *reinterpret_cast<bf16x8*>(&fr);
          const int kvstep = kvt * 2 + ksl;
#pragma unroll
          for (int dt = 0; dt < 4; ++dt) {
            int db = (dt * 32 + l31) * 128 + kvstep * 32 + hi * 16;
            db ^= ((db >> 7) & 7) << 4;
            bf16x8 vf = *reinterpret_cast<const bf16x8*>(VsB + db);
            o_[dt] = __builtin_amdgcn_mfma_f32_32x32x16_bf16(vf, pf, o_[dt], 0, 0, 0);
          }
        }
      }
    }
  }
  // O^T: lane holds q = qglob, d = dt*32 + 8g + 4hi + (0..3) per reg group
  const float inv_l = 1.0f / l_;
  u16* optr = &O[(size_t)qglob * HDIM + h * HEAD_D];
#pragma unroll
  for (int dt = 0; dt < 4; ++dt)
#pragma unroll
    for (int g = 0; g < 4; ++g) {
      ushort4 pk;
      pk.x = f2bf(o_[dt][4 * g + 0] * inv_l);
      pk.y = f2bf(o_[dt][4 * g + 1] * inv_l);
      pk.z = f2bf(o_[dt][4 * g + 2] * inv_l);
      pk.w = f2bf(o_[dt][4 * g + 3] * inv_l);
      *reinterpret_cast<ushort4*>(&optr[dt * 32 + g * 8 + hi * 4]) = pk;
    }
}

extern "C" void kernel_launch(void* const* d_in, const int* in_sizes, int n_in,
                              void* d_out, int out_size, void* d_ws, size_t ws_size,
                              hipStream_t stream) {
  const float* hs = (const float*)d_in[0];
  const float* wq = (const float*)d_in[1];
  const float* wk = (const float*)d_in[2];
  const float* wv = (const float*)d_in[3];
  const float* wo = (const float*)d_in[4];

  char* ws = (char*)d_ws;
  size_t off = 0;
  auto alloc = [&](size_t bytes) {
    void* p = ws + off;
    off += (bytes + 255) & ~(size_t)255;
    return p;
  };
  u16* Xb = (u16*)alloc((size_t)S_LEN * HDIM * 2);
  u16* WqT = (u16*)alloc((size_t)HDIM * HDIM * 2);
  u16* WkT = (u16*)alloc((size_t)KVDIM * HDIM * 2);
  u16* WvT = (u16*)alloc((size_t)KVDIM * HDIM * 2);
  u16* WoT = (u16*)alloc((size_t)HDIM * HDIM * 2);
  u16* Qb = (u16*)alloc((size_t)S_LEN * HDIM * 2);
  u16* Kb = (u16*)alloc((size_t)S_LEN * KVDIM * 2);
  u16* VTb = (u16*)alloc((size_t)KVDIM * S_LEN * 2);  // V^T [512][4096]
  u16* Ab = (u16*)alloc((size_t)S_LEN * HDIM * 2);
  float* cosT = (float*)alloc((size_t)S_LEN * 64 * 4);
  float* sinT = (float*)alloc((size_t)S_LEN * 64 * 4);
  if (off > ws_size) return;  // workspace too small; avoid OOB

  // 1. cast hidden to bf16
  k_cast_bf16<<<dim3(S_LEN * HDIM / 8 / 256), dim3(256), 0, stream>>>(hs, Xb, S_LEN * HDIM / 8);
  // 2. transpose weights to [N][K] bf16
  k_transpose_cast<<<dim3(HDIM / 32, HDIM / 32), dim3(32, 8), 0, stream>>>(wq, WqT, HDIM, HDIM);
  k_transpose_cast<<<dim3(KVDIM / 32, HDIM / 32), dim3(32, 8), 0, stream>>>(wk, WkT, HDIM, KVDIM);
  k_transpose_cast<<<dim3(KVDIM / 32, HDIM / 32), dim3(32, 8), 0, stream>>>(wv, WvT, HDIM, KVDIM);
  k_transpose_cast<<<dim3(HDIM / 32, HDIM / 32), dim3(32, 8), 0, stream>>>(wo, WoT, HDIM, HDIM);
  // 3. rope table
  k_rope_table<<<dim3(S_LEN * 64 / 256), dim3(256), 0, stream>>>(cosT, sinT);
  // 4. merged QKV projection (V written transposed)
  k_gemm_qkv<<<dim3(32, 24), dim3(256), 0, stream>>>(Xb, WqT, WkT, WvT, Qb, Kb, VTb);
  // 5. rope on Q, K
  k_rope_apply<<<dim3(S_LEN * HDIM / 8 / 256), dim3(256), 0, stream>>>(Qb, cosT, sinT, HDIM);
  k_rope_apply<<<dim3(S_LEN * KVDIM / 8 / 256), dim3(256), 0, stream>>>(Kb, cosT, sinT, KVDIM);
  // 6. attention (4-wave, 32x32 MFMA, complementary pairing)
  k_attn<<<dim3(512), dim3(256), 0, stream>>>(Qb, Kb, VTb, Ab);
  // 7. output projection -> f32
  k_gemm_bt<<<dim3(32, 16), dim3(256), 0, stream>>>(Ab, WoT, (float*)d_out, S_LEN, HDIM, HDIM);
}